// Round 6
// baseline (339.438 us; speedup 1.0000x reference)
//
#include <hip/hip_runtime.h>
#include <hip/hip_bf16.h>
#include <math.h>

typedef __hip_bfloat16 bf16;
typedef float f32x4 __attribute__((ext_vector_type(4)));
typedef float f32x2 __attribute__((ext_vector_type(2)));
typedef short short8 __attribute__((ext_vector_type(8)));
typedef short short4v __attribute__((ext_vector_type(4)));

#define NRAYS 4096
#define NSAMP 256
#define RESG  128
#define RS2   16384      // 128*128 (x stride)
#define RS3   2097152    // 128^3   (channel stride)
#define ACT_SHIFT (-4.59511985013459f)

// ---- ws layout ----
#define OFLAG 0
#define OBIAS 16        // b0@16, b1@80, b2@144, b3(16 padded)@224
#define ORO   272       // rays_o fp32 [4096*3]
#define ORD   12560     // rays_d normalized
#define OVD   24848     // viewdirs normalized
#define FRAG_BYTE_OFF 148544
#define LATIL_BYTE_OFF 1048576ULL            // ushort [128^3][16]  (67.1 MB)
#define NRMIL_BYTE_OFF 68157440ULL           // f32x4  [128^3]      (33.5 MB)
#define WS_NEED        101711872ULL

__device__ __forceinline__ float ldT(const float* p, size_t i){ return p[i]; }
__device__ __forceinline__ float ldT(const bf16*  p, size_t i){ return __bfloat162float(p[i]); }

// RNE float->bf16 bits (manual bit math; cold/fallback paths)
__device__ __forceinline__ unsigned short f2bu(float f){
  unsigned int x = __float_as_uint(f);
  unsigned int r = (x + 0x7FFFu + ((x >> 16) & 1u)) >> 16;
  return (unsigned short)r;
}
// native RNE convert — compiler lowers to hw v_cvt (schedulable, unlike asm)
__device__ __forceinline__ unsigned short f2bn(float f){
  union { __hip_bfloat16 h; unsigned short u; } cv;
  cv.h = __float2bfloat16(f);
  return cv.u;
}
__device__ __forceinline__ float bu2f(short s){
  return __uint_as_float(((unsigned int)(unsigned short)s) << 16);
}
// HW packed RNE f32->bf16 (memory-bound stage kernel only)
__device__ __forceinline__ unsigned int pkbf(float lo, float hi){
  unsigned int r;
  asm("v_cvt_pk_bf16_f32 %0, %1, %2" : "=v"(r) : "v"(lo), "v"(hi));
  return r;
}
union SU { short8 s; unsigned int u[4]; };

// prep work partition (bid within [0,53)):
#define PREP_BLOCKS 53

template<typename T>
__device__ void fill_ws_part(const void* W0,const void* b0,const void* W1,const void* b1,
                             const void* W2,const void* b2,const void* W3,const void* b3,
                             const void* ro,const void* rd,const void* vd,
                             float* __restrict__ wb, int bid, int tid, bool isf32)
{
  const T* tW0=(const T*)W0; const T* tb0=(const T*)b0;
  const T* tW1=(const T*)W1; const T* tb1=(const T*)b1;
  const T* tW2=(const T*)W2; const T* tb2=(const T*)b2;
  const T* tW3=(const T*)W3; const T* tb3=(const T*)b3;
  const T* tro=(const T*)ro; const T* trd=(const T*)rd; const T* tvd=(const T*)vd;

  unsigned short* fu = (unsigned short*)((char*)wb + FRAG_BYTE_OFF);

  if (bid < 16){
    const int r = bid*256 + tid;
    float ox = ldT(tro, r*3+0), oy = ldT(tro, r*3+1), oz = ldT(tro, r*3+2);
    wb[ORO+r*3+0]=ox; wb[ORO+r*3+1]=oy; wb[ORO+r*3+2]=oz;
    float dx = ldT(trd, r*3+0), dy = ldT(trd, r*3+1), dz = ldT(trd, r*3+2);
    float dn = 1.0f / sqrtf(dx*dx+dy*dy+dz*dz);
    wb[ORD+r*3+0]=dx*dn; wb[ORD+r*3+1]=dy*dn; wb[ORD+r*3+2]=dz*dn;
    float vx = ldT(tvd, r*3+0), vy = ldT(tvd, r*3+1), vz = ldT(tvd, r*3+2);
    float vn = 1.0f / sqrtf(vx*vx+vy*vy+vz*vz);
    wb[OVD+r*3+0]=vx*vn; wb[OVD+r*3+1]=vy*vn; wb[OVD+r*3+2]=vz*vn;
  } else if (bid < 32){
    // mfma_f32_16x16x32_bf16 B layout:
    //   lane holds B[k = ks*32 + (lane>>4)*8 + j][n = nt*16 + (lane&15)]
    const int idx = (bid-16)*256 + tid;
    int blk = idx >> 9, rem = idx & 511, lane = rem >> 3, j = rem & 7;
    int nt = blk >> 1, ks = blk & 1;
    int k = ks*32 + ((lane>>4)<<3) + j, n = nt*16 + (lane & 15);
    float v = (k < 54) ? ldT(tW0, k*64 + n) : 0.0f;
    fu[idx] = f2bu(v);
  } else if (bid < 48){
    const int idx = (bid-32)*256 + tid;
    int blk = idx >> 9, rem = idx & 511, lane = rem >> 3, j = rem & 7;
    int nt = blk >> 1, ks = blk & 1;
    int k = ks*32 + ((lane>>4)<<3) + j, n = nt*16 + (lane & 15);
    fu[4096+idx] = f2bu(ldT(tW1, k*64 + n));
    fu[8192+idx] = f2bu(ldT(tW2, k*64 + n));
  } else if (bid < 52){
    const int idx = (bid-48)*256 + tid;   // 0..1023
    int blk = idx >> 9, rem = idx & 511, lane = rem >> 3, j = rem & 7;
    int ks = blk;
    int k = ks*32 + ((lane>>4)<<3) + j, n = lane & 15;
    float v = (n < 3) ? ldT(tW3, k*3 + n) : 0.0f;
    fu[12288+idx] = f2bu(v);
  } else {
    if (tid < 64){
      wb[16+tid]  = ldT(tb0, tid);
      wb[80+tid]  = ldT(tb1, tid);
      wb[144+tid] = ldT(tb2, tid);
    }
    if (tid < 16) wb[224+tid] = (tid < 3) ? ldT(tb3, tid) : 0.0f;
    if (tid == 0) wb[OFLAG] = isf32 ? 1.0f : 0.0f;
  }
}

// ================= fused stage kernel: prep + latent-il + normals-il =========
// blocks [0,64):        prep partition (53 used)
// blocks [64,1088):     latent [16][128^3] -> bf16 [128^3][16], 8 voxels/thread
//                       (dwordx4 reads per plane — 16B/lane, m13-style)
// blocks [1088,3136):   normals [3][128^3] -> f32x4 [128^3], 4 voxels/thread,
//                       lane-contiguous 16B stores
#define STAGE_BLOCKS 3136

__global__ __launch_bounds__(256)
void stage(const void* W0,const void* b0,const void* W1,const void* b1,
           const void* W2,const void* b2,const void* W3,const void* b3,
           const void* ro,const void* rd,const void* vd,
           const void* __restrict__ latent, const void* __restrict__ normals,
           float* __restrict__ wb)
{
  __shared__ int s_f32;
  const int tid = threadIdx.x;
  const int bid = blockIdx.x;
  if (tid == 0) s_f32 = 0;
  __syncthreads();
  {
    // each block independently detects fp32 vs bf16 inputs from W1's bit pattern
    const bf16* t1 = (const bf16*)W1;
    float a = fabsf(__bfloat162float(t1[2*tid]));
    float b = fabsf(__bfloat162float(t1[2*tid+1]));
    if (!(a < 100.0f) || !(b < 100.0f)) atomicOr(&s_f32, 1);
  }
  __syncthreads();
  const bool isf32 = (s_f32 != 0);

  if (bid < 64){
    if (bid < PREP_BLOCKS){
      if (isf32) fill_ws_part<float>(W0,b0,W1,b1,W2,b2,W3,b3,ro,rd,vd,wb,bid,tid,true);
      else       fill_ws_part<bf16 >(W0,b0,W1,b1,W2,b2,W3,b3,ro,rd,vd,wb,bid,tid,false);
    }
  } else if (bid < 1088){
    unsigned short* lat_il = (unsigned short*)((char*)wb + LATIL_BYTE_OFF);
    const int base = (bid-64)*2048 + tid*8;   // 8 consecutive voxels
    if (isf32){
      const float* p = (const float*)latent;
#pragma unroll
      for (int half = 0; half < 2; half++){
        const int vb = base + half*4;
        f32x4 q[16];
#pragma unroll
        for (int c = 0; c < 16; c++)
          q[c] = *(const f32x4*)&p[(size_t)c*RS3 + vb];
#pragma unroll
        for (int j = 0; j < 4; j++){
          SU lo, hi;
#pragma unroll
          for (int c = 0; c < 4; c++){
            lo.u[c] = pkbf(q[2*c  ][j], q[2*c+1][j]);
            hi.u[c] = pkbf(q[2*c+8][j], q[2*c+9][j]);
          }
          unsigned short* qq = &lat_il[(size_t)(vb+j) << 4];
          *(short8*)&qq[0] = lo.s;
          *(short8*)&qq[8] = hi.s;
        }
      }
    } else {
      const unsigned short* p = (const unsigned short*)latent;
      short8 pl[16];
#pragma unroll
      for (int c = 0; c < 16; c++)
        pl[c] = *(const short8*)&p[(size_t)c*RS3 + base];
#pragma unroll
      for (int j = 0; j < 8; j++){
        short8 lo, hi;
#pragma unroll
        for (int c = 0; c < 8; c++){ lo[c] = pl[c][j]; hi[c] = pl[c+8][j]; }
        unsigned short* qq = &lat_il[(size_t)(base+j) << 4];
        *(short8*)&qq[0] = lo;
        *(short8*)&qq[8] = hi;
      }
    }
  } else {
    // normals: block covers 1024 voxels; store j is lane-contiguous 4KB
    f32x4* nrm_il = (f32x4*)((char*)wb + NRMIL_BYTE_OFF);
    const int nb = (bid-1088)*1024;
    if (isf32){
      const float* p = (const float*)normals;
#pragma unroll
      for (int j = 0; j < 4; j++){
        const int v = nb + j*256 + tid;
        nrm_il[v] = (f32x4){ p[v], p[(size_t)RS3+v], p[(size_t)2*RS3+v], 0.0f };
      }
    } else {
      const unsigned short* p = (const unsigned short*)normals;
#pragma unroll
      for (int j = 0; j < 4; j++){
        const int v = nb + j*256 + tid;
        nrm_il[v] = (f32x4){ bu2f(p[v]), bu2f(p[(size_t)RS3+v]),
                             bu2f(p[(size_t)2*RS3+v]), 0.0f };
      }
    }
  }
}

// standalone prep (fallback path only)
__global__ __launch_bounds__(256)
void prep(const void* W0,const void* b0,const void* W1,const void* b1,
          const void* W2,const void* b2,const void* W3,const void* b3,
          const void* ro,const void* rd,const void* vd,
          float* __restrict__ wb)
{
  __shared__ int s_f32;
  const int tid = threadIdx.x;
  const int bid = blockIdx.x;
  if (tid == 0) s_f32 = 0;
  __syncthreads();
  {
    const bf16* t1 = (const bf16*)W1;
    float a = fabsf(__bfloat162float(t1[2*tid]));
    float b = fabsf(__bfloat162float(t1[2*tid+1]));
    if (!(a < 100.0f) || !(b < 100.0f)) atomicOr(&s_f32, 1);
  }
  __syncthreads();
  const bool isf32 = (s_f32 != 0);
  if (isf32) fill_ws_part<float>(W0,b0,W1,b1,W2,b2,W3,b3,ro,rd,vd,wb,bid,tid,true);
  else       fill_ws_part<bf16 >(W0,b0,W1,b1,W2,b2,W3,b3,ro,rd,vd,wb,bid,tid,false);
}

// ---- fast render: one block/ray, thread i = sample i, interleaved grids ----
__global__ __launch_bounds__(256, 4)
void render_fast(const float* __restrict__ wb, float* __restrict__ out)
{
  const int ray  = blockIdx.x;
  const int i    = threadIdx.x;
  const int lane = i & 63;
  const int wv   = i >> 6;
  const int quad = lane >> 4;
  const int n15  = lane & 15;
  const int wbase = wv * 64;

  __shared__ unsigned short act[NSAMP*72];   // row stride 72 bf16 (144 B)
  __shared__ float sh_w[NSAMP];
  __shared__ float sh_wt[4];
  __shared__ float red[4][8];
  __shared__ float red_rgb[4][16];

  const unsigned short* lat_il = (const unsigned short*)((const char*)wb + LATIL_BYTE_OFF);
  const f32x4* nrm_il = (const f32x4*)((const char*)wb + NRMIL_BYTE_OFF);

  const float ox = wb[ORO+ray*3+0], oy = wb[ORO+ray*3+1], oz = wb[ORO+ray*3+2];
  const float dx = wb[ORD+ray*3+0], dy = wb[ORD+ray*3+1], dz = wb[ORD+ray*3+2];
  const float vx = wb[OVD+ray*3+0], vy = wb[OVD+ray*3+1], vz = wb[OVD+ray*3+2];

  const float t  = 0.2f + (2.8f/255.0f) * (float)i;
  const float px = ox + dx*t, py = oy + dy*t, pz = oz + dz*t;
  const bool inb = (px >= -1.0f) & (px <= 1.0f) & (py >= -1.0f) & (py <= 1.0f)
                 & (pz >= -1.0f) & (pz <= 1.0f);

  float alpha = 0.0f, nx = 0.0f, ny = 0.0f, nz = 0.0f;
  unsigned short* arow = &act[i*72];

  if (inb) {
    float ux = fminf(fmaxf((px+1.0f)*0.5f, 0.0f), 1.0f) * 127.0f;
    float uy = fminf(fmaxf((py+1.0f)*0.5f, 0.0f), 1.0f) * 127.0f;
    float uz = fminf(fmaxf((pz+1.0f)*0.5f, 0.0f), 1.0f) * 127.0f;
    int x0 = (int)floorf(ux); x0 = x0 > 126 ? 126 : (x0 < 0 ? 0 : x0);
    int y0 = (int)floorf(uy); y0 = y0 > 126 ? 126 : (y0 < 0 ? 0 : y0);
    int z0 = (int)floorf(uz); z0 = z0 > 126 ? 126 : (z0 < 0 ? 0 : z0);
    float fx = ux - (float)x0, fy = uy - (float)y0, fz = uz - (float)z0;
    const float gx = 1.0f - fx, gy = 1.0f - fy, gz = 1.0f - fz;

    const int vb = (x0<<14) + (y0<<7) + z0;
    const unsigned short* Lp = lat_il + ((size_t)vb<<4);
    const f32x4* Np = nrm_il + vb;

    // 16 channels as 8 packed f32x2 pairs (lets LLVM form v_pk_fma_f32)
    f32x2 ch2[8];
#pragma unroll
    for (int w = 0; w < 8; w++) ch2[w] = (f32x2){0.f, 0.f};
    float nr0 = 0.0f, nr1 = 0.0f, nr2 = 0.0f;

    const int   loff[4] = {0, 1<<18, 1<<11, (1<<18)+(1<<11)};   // ushort offsets
    const int   noff[4] = {0, 16384, 128, 16384+128};           // f32x4 offsets
    const float wxy[4]  = {gx*gy, fx*gy, gx*fy, fx*fy};

#pragma unroll
    for (int cr = 0; cr < 4; cr++){
      const unsigned short* p = Lp + loff[cr];
      SU A0, A1, B0, B1;
      A0.s = *(const short8*)(p);        // z0, ch0..7
      A1.s = *(const short8*)(p+8);      // z0, ch8..15
      B0.s = *(const short8*)(p+16);     // z1, ch0..7
      B1.s = *(const short8*)(p+24);     // z1, ch8..15
      const float wz0 = wxy[cr]*gz, wz1 = wxy[cr]*fz;
      const f32x2 w0v = (f32x2){wz0, wz0}, w1v = (f32x2){wz1, wz1};
#pragma unroll
      for (int w = 0; w < 4; w++){
        f32x2 va = (f32x2){__uint_as_float(A0.u[w] << 16), __uint_as_float(A0.u[w] & 0xFFFF0000u)};
        f32x2 vb = (f32x2){__uint_as_float(B0.u[w] << 16), __uint_as_float(B0.u[w] & 0xFFFF0000u)};
        ch2[w] += w0v*va + w1v*vb;
        f32x2 vc = (f32x2){__uint_as_float(A1.u[w] << 16), __uint_as_float(A1.u[w] & 0xFFFF0000u)};
        f32x2 vd = (f32x2){__uint_as_float(B1.u[w] << 16), __uint_as_float(B1.u[w] & 0xFFFF0000u)};
        ch2[w+4] += w0v*vc + w1v*vd;
      }
      f32x4 n0 = Np[noff[cr]];
      f32x4 n1 = Np[noff[cr]+1];
      nr0 += wz0*n0[0] + wz1*n1[0];
      nr1 += wz0*n0[1] + wz1*n1[1];
      nr2 += wz0*n0[2] + wz1*n1[2];
    }

    float chv[16];
#pragma unroll
    for (int w = 0; w < 8; w++){ chv[2*w] = ch2[w][0]; chv[2*w+1] = ch2[w][1]; }

    float xs = chv[0] + ACT_SHIFT;
    float sp = xs > 15.0f ? xs : log1pf(__expf(xs));
    alpha = 1.0f - __expf(-sp * 0.5f);

    float nn  = sqrtf(nr0*nr0 + nr1*nr1 + nr2*nr2);
    float ninv = 1.0f / fmaxf(nn, 1e-12f);
    nx = nr0*ninv; ny = nr1*ninv; nz = nr2*ninv;

    float dt = -(vx*nx + vy*ny + vz*nz);
    float rx = 2.0f*dt*nx + vx, ry = 2.0f*dt*ny + vy, rz = 2.0f*dt*nz + vz;

    // f=0 via sincos; f=1..5 via double-angle recurrence
    float sX[6], sY[6], sZ[6], cX[6], cY[6], cZ[6];
    __sincosf(rx, &sX[0], &cX[0]);
    __sincosf(ry, &sY[0], &cY[0]);
    __sincosf(rz, &sZ[0], &cZ[0]);
#pragma unroll
    for (int f = 1; f < 6; f++){
      sX[f] = 2.0f*sX[f-1]*cX[f-1];  cX[f] = fmaf(-2.0f*sX[f-1], sX[f-1], 1.0f);
      sY[f] = 2.0f*sY[f-1]*cY[f-1];  cY[f] = fmaf(-2.0f*sY[f-1], sY[f-1], 1.0f);
      sZ[f] = 2.0f*sZ[f-1]*cZ[f-1];  cZ[f] = fmaf(-2.0f*sZ[f-1], sZ[f-1], 1.0f);
    }

    // feat -> LDS in 16-element chunks (native converts — compiler emits hw cvt)
    short8 v0, v1;
#pragma unroll
    for (int j = 0; j < 8; j++) v0[j] = (short)f2bn(chv[1+j]);
#pragma unroll
    for (int j = 0; j < 7; j++) v1[j] = (short)f2bn(chv[9+j]);
    v1[7] = (short)f2bn(rx);
    *(short8*)&arow[0] = v0; *(short8*)&arow[8] = v1;
    v0[0]=(short)f2bn(ry);     v0[1]=(short)f2bn(rz);
    v0[2]=(short)f2bn(sX[0]);  v0[3]=(short)f2bn(sY[0]);  v0[4]=(short)f2bn(sZ[0]);
    v0[5]=(short)f2bn(sX[1]);  v0[6]=(short)f2bn(sY[1]);  v0[7]=(short)f2bn(sZ[1]);
    v1[0]=(short)f2bn(sX[2]);  v1[1]=(short)f2bn(sY[2]);  v1[2]=(short)f2bn(sZ[2]);
    v1[3]=(short)f2bn(sX[3]);  v1[4]=(short)f2bn(sY[3]);  v1[5]=(short)f2bn(sZ[3]);
    v1[6]=(short)f2bn(sX[4]);  v1[7]=(short)f2bn(sY[4]);
    *(short8*)&arow[16] = v0; *(short8*)&arow[24] = v1;
    v0[0]=(short)f2bn(sZ[4]);  v0[1]=(short)f2bn(sX[5]);
    v0[2]=(short)f2bn(sY[5]);  v0[3]=(short)f2bn(sZ[5]);
    v0[4]=(short)f2bn(cX[0]);  v0[5]=(short)f2bn(cY[0]);  v0[6]=(short)f2bn(cZ[0]);
    v0[7]=(short)f2bn(cX[1]);
    v1[0]=(short)f2bn(cY[1]);  v1[1]=(short)f2bn(cZ[1]);
    v1[2]=(short)f2bn(cX[2]);  v1[3]=(short)f2bn(cY[2]);  v1[4]=(short)f2bn(cZ[2]);
    v1[5]=(short)f2bn(cX[3]);  v1[6]=(short)f2bn(cY[3]);  v1[7]=(short)f2bn(cZ[3]);
    *(short8*)&arow[32] = v0; *(short8*)&arow[40] = v1;
    v0[0]=(short)f2bn(cX[4]);  v0[1]=(short)f2bn(cY[4]);  v0[2]=(short)f2bn(cZ[4]);
    v0[3]=(short)f2bn(cX[5]);  v0[4]=(short)f2bn(cY[5]);  v0[5]=(short)f2bn(cZ[5]);
    v0[6]=0; v0[7]=0;
#pragma unroll
    for (int j = 0; j < 8; j++) v1[j] = 0;
    *(short8*)&arow[48] = v0; *(short8*)&arow[56] = v1;
  } else {
    short8 z;
#pragma unroll
    for (int j = 0; j < 8; j++) z[j] = 0;
#pragma unroll
    for (int c = 0; c < 8; c++) *(short8*)&arow[c*8] = z;
  }

  // ---- transmittance: wave shfl scan + cross-wave prefix ----
  float xv = fmaxf(1.0f - alpha, 1e-10f);
  float incl = xv;
#pragma unroll
  for (int off = 1; off < 64; off <<= 1){
    float y = __shfl_up(incl, off, 64);
    if (lane >= off) incl *= y;
  }
  float excl = __shfl_up(incl, 1, 64);
  if (lane == 0) excl = 1.0f;
  if (lane == 63) sh_wt[wv] = incl;
  __syncthreads();   // B1

  float pre = 1.0f;
#pragma unroll
  for (int k = 0; k < 4; k++) if (k < wv) pre *= sh_wt[k];
  const float last = sh_wt[0]*sh_wt[1]*sh_wt[2]*sh_wt[3];
  const float av = pre * excl;
  const float w  = alpha * av;
  sh_w[i] = w;

  float* outw = out + 36864;            // weights      (4096*256)
  float* outa = out + 36864 + 1048576;  // alphainv_cum (4096*257)
  outw[ray*NSAMP + i] = w;
  outa[ray*(NSAMP+1) + i] = av;
  if (i == NSAMP-1) outa[ray*(NSAMP+1) + NSAMP] = last;

  {
    float vals[5] = { w*t, w, w*nx, w*ny, w*nz };
#pragma unroll
    for (int v = 0; v < 5; v++){
      float s = vals[v];
#pragma unroll
      for (int m = 32; m > 0; m >>= 1) s += __shfl_xor(s, m, 64);
      if (lane == 0) red[wv][v] = s;
    }
  }
  __syncthreads();   // B2
  if (i == 0){
    float s0 = red[0][0]+red[1][0]+red[2][0]+red[3][0];
    float s1 = red[0][1]+red[1][1]+red[2][1]+red[3][1];
    float s2 = red[0][2]+red[1][2]+red[2][2]+red[3][2];
    float s3 = red[0][3]+red[1][3]+red[2][3]+red[3][3];
    float s4 = red[0][4]+red[1][4]+red[2][4]+red[3][4];
    const float dm = s0 + last * 3.0f;
    float* o1 = out + 12288; o1[ray] = dm;
    float* o2 = out + 16384; o2[ray] = 1.0f / dm;
    float* o3 = out + 20480; o3[ray] = s1;
    float* o4 = out + 24576;
    o4[ray*3+0] = s2; o4[ray*3+1] = s3; o4[ray*3+2] = s4;
  }

  // ---- MLP via MFMA: wave handles rows [wbase, wbase+64) ----
  const short8* fr = (const short8*)((const char*)wb + FRAG_BYTE_OFF);

#pragma unroll
  for (int l = 0; l < 3; l++){
    const int fbase = l * 512;
    f32x4 acc[4][4];
#pragma unroll
    for (int mt = 0; mt < 4; mt++)
#pragma unroll
      for (int nt = 0; nt < 4; nt++) acc[mt][nt] = (f32x4){0.f,0.f,0.f,0.f};

#pragma unroll
    for (int ks = 0; ks < 2; ks++){
      short8 a[4], b[4];
#pragma unroll
      for (int mt = 0; mt < 4; mt++)
        a[mt] = *(const short8*)&act[(wbase + mt*16 + n15)*72 + ks*32 + quad*8];
#pragma unroll
      for (int nt = 0; nt < 4; nt++)
        b[nt] = fr[fbase + (nt*2+ks)*64 + lane];
#pragma unroll
      for (int mt = 0; mt < 4; mt++)
#pragma unroll
        for (int nt = 0; nt < 4; nt++)
          acc[mt][nt] = __builtin_amdgcn_mfma_f32_16x16x32_bf16(a[mt], b[nt], acc[mt][nt], 0, 0, 0);
    }
    __syncthreads();
#pragma unroll
    for (int nt = 0; nt < 4; nt++){
      const float bn = wb[OBIAS + l*64 + nt*16 + n15];
#pragma unroll
      for (int mt = 0; mt < 4; mt++){
#pragma unroll
        for (int r = 0; r < 4; r++){
          float vv = fmaxf(acc[mt][nt][r] + bn, 0.0f);
          act[(wbase + mt*16 + quad*4 + r)*72 + nt*16 + n15] = f2bn(vv);
        }
      }
    }
    __syncthreads();
  }

  // layer 3 + fused weighted rgb reduction
  {
    f32x4 acc3[4];
#pragma unroll
    for (int mt = 0; mt < 4; mt++) acc3[mt] = (f32x4){0.f,0.f,0.f,0.f};
#pragma unroll
    for (int ks = 0; ks < 2; ks++){
      short8 a[4];
#pragma unroll
      for (int mt = 0; mt < 4; mt++)
        a[mt] = *(const short8*)&act[(wbase + mt*16 + n15)*72 + ks*32 + quad*8];
      short8 b = fr[1536 + ks*64 + lane];
#pragma unroll
      for (int mt = 0; mt < 4; mt++)
        acc3[mt] = __builtin_amdgcn_mfma_f32_16x16x32_bf16(a[mt], b, acc3[mt], 0, 0, 0);
    }
    const float bn3 = wb[OBIAS + 208 + n15];
    float p = 0.0f;
#pragma unroll
    for (int mt = 0; mt < 4; mt++){
#pragma unroll
      for (int r = 0; r < 4; r++){
        const float wr = sh_w[wbase + mt*16 + quad*4 + r];
        const float logit = acc3[mt][r] + bn3;
        p += wr * (1.0f / (1.0f + __expf(-logit)));
      }
    }
    p += __shfl_xor(p, 16, 64);
    p += __shfl_xor(p, 32, 64);
    if (lane < 16) red_rgb[wv][lane] = p;
  }
  __syncthreads();   // B3
  if (i < 3){
    float s = red_rgb[0][i] + red_rgb[1][i] + red_rgb[2][i] + red_rgb[3][i];
    out[ray*3+i] = s + last;   // + BG*last, BG=1
  }
}

// ================= fallback path (ws too small) =================
template<typename GT>
__device__ __forceinline__ void render_body(const GT* __restrict__ latent,
                                            const GT* __restrict__ normals,
                                            const float* __restrict__ wb,
                                            float* __restrict__ out)
{
  const int ray  = blockIdx.x;
  const int i    = threadIdx.x;
  const int lane = i & 63;
  const int wv   = i >> 6;
  const int quad = lane >> 4;
  const int n15  = lane & 15;
  const int wbase = wv * 64;

  __shared__ unsigned short act[NSAMP*72];
  __shared__ float sh_w[NSAMP];
  __shared__ float sh_wt[4];
  __shared__ float red[4][8];
  __shared__ float red_rgb[4][16];

  const float ox = wb[ORO+ray*3+0], oy = wb[ORO+ray*3+1], oz = wb[ORO+ray*3+2];
  const float dx = wb[ORD+ray*3+0], dy = wb[ORD+ray*3+1], dz = wb[ORD+ray*3+2];
  const float vx = wb[OVD+ray*3+0], vy = wb[OVD+ray*3+1], vz = wb[OVD+ray*3+2];

  const float t  = 0.2f + (2.8f/255.0f) * (float)i;
  const float px = ox + dx*t, py = oy + dy*t, pz = oz + dz*t;
  const bool inb = (px >= -1.0f) & (px <= 1.0f) & (py >= -1.0f) & (py <= 1.0f)
                 & (pz >= -1.0f) & (pz <= 1.0f);

  float alpha = 0.0f, nx = 0.0f, ny = 0.0f, nz = 0.0f;
  float fv[64];
#pragma unroll
  for (int k = 0; k < 64; k++) fv[k] = 0.0f;

  if (inb) {
    float ux = fminf(fmaxf((px+1.0f)*0.5f, 0.0f), 1.0f) * 127.0f;
    float uy = fminf(fmaxf((py+1.0f)*0.5f, 0.0f), 1.0f) * 127.0f;
    float uz = fminf(fmaxf((pz+1.0f)*0.5f, 0.0f), 1.0f) * 127.0f;
    int x0 = (int)floorf(ux); x0 = x0 > 126 ? 126 : (x0 < 0 ? 0 : x0);
    int y0 = (int)floorf(uy); y0 = y0 > 126 ? 126 : (y0 < 0 ? 0 : y0);
    int z0 = (int)floorf(uz); z0 = z0 > 126 ? 126 : (z0 < 0 ? 0 : z0);
    float fx = ux - (float)x0, fy = uy - (float)y0, fz = uz - (float)z0;
    const int base = x0*RS2 + y0*RESG + z0;
    const float gx = 1.0f - fx, gy = 1.0f - fy, gz = 1.0f - fz;
    const float w000 = gx*gy*gz, w100 = fx*gy*gz, w010 = gx*fy*gz, w001 = gx*gy*fz;
    const float w110 = fx*fy*gz, w101 = fx*gy*fz, w011 = gx*fy*fz, w111 = fx*fy*fz;

    float ch[19];
#pragma unroll
    for (int c = 0; c < 19; c++){
      const GT* g = (c < 16 ? latent + c*RS3 : normals + (c-16)*RS3) + base;
      ch[c] = w000*ldT(g,0)        + w100*ldT(g,RS2)
            + w010*ldT(g,RESG)     + w001*ldT(g,1)
            + w110*ldT(g,RS2+RESG) + w101*ldT(g,RS2+1)
            + w011*ldT(g,RESG+1)   + w111*ldT(g,RS2+RESG+1);
    }

    float xs = ch[0] + ACT_SHIFT;
    float sp = xs > 15.0f ? xs : log1pf(__expf(xs));
    alpha = 1.0f - __expf(-sp * 0.5f);

    float nn  = sqrtf(ch[16]*ch[16] + ch[17]*ch[17] + ch[18]*ch[18]);
    float ninv = 1.0f / fmaxf(nn, 1e-12f);
    nx = ch[16]*ninv; ny = ch[17]*ninv; nz = ch[18]*ninv;

    float dt = -(vx*nx + vy*ny + vz*nz);
    float rx = 2.0f*dt*nx + vx, ry = 2.0f*dt*ny + vy, rz = 2.0f*dt*nz + vz;

#pragma unroll
    for (int k = 0; k < 15; k++) fv[k] = ch[k+1];
    fv[15] = rx; fv[16] = ry; fv[17] = rz;
#pragma unroll
    for (int f = 0; f < 6; f++){
      float s = (float)(1 << f);
      fv[18 + f*3 + 0] = __sinf(rx*s);
      fv[18 + f*3 + 1] = __sinf(ry*s);
      fv[18 + f*3 + 2] = __sinf(rz*s);
      fv[36 + f*3 + 0] = __cosf(rx*s);
      fv[36 + f*3 + 1] = __cosf(ry*s);
      fv[36 + f*3 + 2] = __cosf(rz*s);
    }
  }

#pragma unroll
  for (int c = 0; c < 8; c++){
    short8 v;
#pragma unroll
    for (int k = 0; k < 8; k++) v[k] = (short)f2bu(fv[c*8+k]);
    *(short8*)&act[i*72 + c*8] = v;
  }

  float xvv = fmaxf(1.0f - alpha, 1e-10f);
  float incl = xvv;
#pragma unroll
  for (int off = 1; off < 64; off <<= 1){
    float y = __shfl_up(incl, off, 64);
    if (lane >= off) incl *= y;
  }
  float excl = __shfl_up(incl, 1, 64);
  if (lane == 0) excl = 1.0f;
  if (lane == 63) sh_wt[wv] = incl;
  __syncthreads();

  float pre = 1.0f;
#pragma unroll
  for (int k = 0; k < 4; k++) if (k < wv) pre *= sh_wt[k];
  const float last = sh_wt[0]*sh_wt[1]*sh_wt[2]*sh_wt[3];
  const float av = pre * excl;
  const float w  = alpha * av;
  sh_w[i] = w;

  float* outw = out + 36864;
  float* outa = out + 36864 + 1048576;
  outw[ray*NSAMP + i] = w;
  outa[ray*(NSAMP+1) + i] = av;
  if (i == NSAMP-1) outa[ray*(NSAMP+1) + NSAMP] = last;

  {
    float vals[5] = { w*t, w, w*nx, w*ny, w*nz };
#pragma unroll
    for (int v = 0; v < 5; v++){
      float s = vals[v];
#pragma unroll
      for (int m = 32; m > 0; m >>= 1) s += __shfl_xor(s, m, 64);
      if (lane == 0) red[wv][v] = s;
    }
  }
  __syncthreads();
  if (i == 0){
    float s0 = red[0][0]+red[1][0]+red[2][0]+red[3][0];
    float s1 = red[0][1]+red[1][1]+red[2][1]+red[3][1];
    float s2 = red[0][2]+red[1][2]+red[2][2]+red[3][2];
    float s3 = red[0][3]+red[1][3]+red[2][3]+red[3][3];
    float s4 = red[0][4]+red[1][4]+red[2][4]+red[3][4];
    const float dm = s0 + last * 3.0f;
    float* o1 = out + 12288; o1[ray] = dm;
    float* o2 = out + 16384; o2[ray] = 1.0f / dm;
    float* o3 = out + 20480; o3[ray] = s1;
    float* o4 = out + 24576;
    o4[ray*3+0] = s2; o4[ray*3+1] = s3; o4[ray*3+2] = s4;
  }

  const short8* fr = (const short8*)((const char*)wb + FRAG_BYTE_OFF);

#pragma unroll
  for (int l = 0; l < 3; l++){
    const int fbase = l * 512;
    f32x4 acc[4][4];
#pragma unroll
    for (int mt = 0; mt < 4; mt++)
#pragma unroll
      for (int nt = 0; nt < 4; nt++) acc[mt][nt] = (f32x4){0.f,0.f,0.f,0.f};

#pragma unroll
    for (int ks = 0; ks < 2; ks++){
      short8 a[4], b[4];
#pragma unroll
      for (int mt = 0; mt < 4; mt++)
        a[mt] = *(const short8*)&act[(wbase + mt*16 + n15)*72 + ks*32 + quad*8];
#pragma unroll
      for (int nt = 0; nt < 4; nt++)
        b[nt] = fr[fbase + (nt*2+ks)*64 + lane];
#pragma unroll
      for (int mt = 0; mt < 4; mt++)
#pragma unroll
        for (int nt = 0; nt < 4; nt++)
          acc[mt][nt] = __builtin_amdgcn_mfma_f32_16x16x32_bf16(a[mt], b[nt], acc[mt][nt], 0, 0, 0);
    }
    __syncthreads();
#pragma unroll
    for (int nt = 0; nt < 4; nt++){
      const float bn = wb[OBIAS + l*64 + nt*16 + n15];
#pragma unroll
      for (int mt = 0; mt < 4; mt++){
#pragma unroll
        for (int r = 0; r < 4; r++){
          float vv = fmaxf(acc[mt][nt][r] + bn, 0.0f);
          act[(wbase + mt*16 + quad*4 + r)*72 + nt*16 + n15] = f2bu(vv);
        }
      }
    }
    __syncthreads();
  }

  {
    f32x4 acc3[4];
#pragma unroll
    for (int mt = 0; mt < 4; mt++) acc3[mt] = (f32x4){0.f,0.f,0.f,0.f};
#pragma unroll
    for (int ks = 0; ks < 2; ks++){
      short8 a[4];
#pragma unroll
      for (int mt = 0; mt < 4; mt++)
        a[mt] = *(const short8*)&act[(wbase + mt*16 + n15)*72 + ks*32 + quad*8];
      short8 b = fr[1536 + ks*64 + lane];
#pragma unroll
      for (int mt = 0; mt < 4; mt++)
        acc3[mt] = __builtin_amdgcn_mfma_f32_16x16x32_bf16(a[mt], b, acc3[mt], 0, 0, 0);
    }
    const float bn3 = wb[OBIAS + 208 + n15];
    float p = 0.0f;
#pragma unroll
    for (int mt = 0; mt < 4; mt++){
#pragma unroll
      for (int r = 0; r < 4; r++){
        const float wr = sh_w[wbase + mt*16 + quad*4 + r];
        const float logit = acc3[mt][r] + bn3;
        p += wr * (1.0f / (1.0f + __expf(-logit)));
      }
    }
    p += __shfl_xor(p, 16, 64);
    p += __shfl_xor(p, 32, 64);
    if (lane < 16) red_rgb[wv][lane] = p;
  }
  __syncthreads();
  if (i < 3){
    float s = red_rgb[0][i] + red_rgb[1][i] + red_rgb[2][i] + red_rgb[3][i];
    out[ray*3+i] = s + last;
  }
}

__global__ __launch_bounds__(256)
void render_fallback(const void* __restrict__ latent, const void* __restrict__ normals,
                     const float* __restrict__ wb, float* __restrict__ out)
{
  if (wb[OFLAG] > 0.5f)
    render_body<float>((const float*)latent, (const float*)normals, wb, out);
  else
    render_body<bf16 >((const bf16*)latent,  (const bf16*)normals,  wb, out);
}

extern "C" void kernel_launch(void* const* d_in, const int* in_sizes, int n_in,
                              void* d_out, int out_size, void* d_ws, size_t ws_size,
                              hipStream_t stream)
{
  float* wb = (float*)d_ws;
  if (ws_size >= WS_NEED){
    stage<<<STAGE_BLOCKS, 256, 0, stream>>>(d_in[5], d_in[6], d_in[7], d_in[8],
                                            d_in[9], d_in[10], d_in[11], d_in[12],
                                            d_in[0], d_in[1], d_in[2],
                                            d_in[3], d_in[4], wb);
    render_fast<<<NRAYS, 256, 0, stream>>>(wb, (float*)d_out);
  } else {
    prep<<<PREP_BLOCKS, 256, 0, stream>>>(d_in[5], d_in[6], d_in[7], d_in[8],
                                          d_in[9], d_in[10], d_in[11], d_in[12],
                                          d_in[0], d_in[1], d_in[2], wb);
    render_fallback<<<NRAYS, 256, 0, stream>>>(d_in[3], d_in[4], wb, (float*)d_out);
  }
}

// Round 7
// 333.605 us; speedup vs baseline: 1.0175x; 1.0175x over previous
//
#include <hip/hip_runtime.h>
#include <hip/hip_bf16.h>
#include <math.h>

typedef __hip_bfloat16 bf16;
typedef float f32x4 __attribute__((ext_vector_type(4)));
typedef float f32x2 __attribute__((ext_vector_type(2)));
typedef short short8 __attribute__((ext_vector_type(8)));
typedef short short4v __attribute__((ext_vector_type(4)));
typedef unsigned int u32x4 __attribute__((ext_vector_type(4)));

#define NRAYS 4096
#define NSAMP 256
#define RESG  128
#define RS2   16384      // 128*128 (x stride)
#define RS3   2097152    // 128^3   (channel stride)
#define ACT_SHIFT (-4.59511985013459f)

// ---- ws layout ----
#define OFLAG 0
#define OBIAS 16        // b0@16, b1@80, b2@144, b3(16 padded)@224
#define ORO   272       // rays_o fp32 [4096*3]
#define ORD   12560     // rays_d normalized
#define OVD   24848     // viewdirs normalized
#define FRAG_BYTE_OFF 148544
#define LATIL_BYTE_OFF 1048576ULL            // ushort [128^3][16]  (67.1 MB)
#define NRMIL_BYTE_OFF 68157440ULL           // f32x4  [128^3]      (33.5 MB)
#define WS_NEED        101711872ULL

__device__ __forceinline__ float ldT(const float* p, size_t i){ return p[i]; }
__device__ __forceinline__ float ldT(const bf16*  p, size_t i){ return __bfloat162float(p[i]); }

// RNE float->bf16 bits (manual bit math; cold/fallback paths)
__device__ __forceinline__ unsigned short f2bu(float f){
  unsigned int x = __float_as_uint(f);
  unsigned int r = (x + 0x7FFFu + ((x >> 16) & 1u)) >> 16;
  return (unsigned short)r;
}
// native RNE convert — compiler lowers to hw v_cvt (schedulable, unlike asm)
__device__ __forceinline__ unsigned short f2bn(float f){
  union { __hip_bfloat16 h; unsigned short u; } cv;
  cv.h = __float2bfloat16(f);
  return cv.u;
}
__device__ __forceinline__ float bu2f(short s){
  return __uint_as_float(((unsigned int)(unsigned short)s) << 16);
}
// HW packed RNE f32->bf16 (memory-bound stage kernel only)
__device__ __forceinline__ unsigned int pkbf(float lo, float hi){
  unsigned int r;
  asm("v_cvt_pk_bf16_f32 %0, %1, %2" : "=v"(r) : "v"(lo), "v"(hi));
  return r;
}
union SU { short8 s; unsigned int u[4]; };

// prep work partition (bid within [0,53)):
#define PREP_BLOCKS 53

template<typename T>
__device__ void fill_ws_part(const void* W0,const void* b0,const void* W1,const void* b1,
                             const void* W2,const void* b2,const void* W3,const void* b3,
                             const void* ro,const void* rd,const void* vd,
                             float* __restrict__ wb, int bid, int tid, bool isf32)
{
  const T* tW0=(const T*)W0; const T* tb0=(const T*)b0;
  const T* tW1=(const T*)W1; const T* tb1=(const T*)b1;
  const T* tW2=(const T*)W2; const T* tb2=(const T*)b2;
  const T* tW3=(const T*)W3; const T* tb3=(const T*)b3;
  const T* tro=(const T*)ro; const T* trd=(const T*)rd; const T* tvd=(const T*)vd;

  unsigned short* fu = (unsigned short*)((char*)wb + FRAG_BYTE_OFF);

  if (bid < 16){
    const int r = bid*256 + tid;
    float ox = ldT(tro, r*3+0), oy = ldT(tro, r*3+1), oz = ldT(tro, r*3+2);
    wb[ORO+r*3+0]=ox; wb[ORO+r*3+1]=oy; wb[ORO+r*3+2]=oz;
    float dx = ldT(trd, r*3+0), dy = ldT(trd, r*3+1), dz = ldT(trd, r*3+2);
    float dn = 1.0f / sqrtf(dx*dx+dy*dy+dz*dz);
    wb[ORD+r*3+0]=dx*dn; wb[ORD+r*3+1]=dy*dn; wb[ORD+r*3+2]=dz*dn;
    float vx = ldT(tvd, r*3+0), vy = ldT(tvd, r*3+1), vz = ldT(tvd, r*3+2);
    float vn = 1.0f / sqrtf(vx*vx+vy*vy+vz*vz);
    wb[OVD+r*3+0]=vx*vn; wb[OVD+r*3+1]=vy*vn; wb[OVD+r*3+2]=vz*vn;
  } else if (bid < 32){
    // mfma_f32_16x16x32_bf16 B layout:
    //   lane holds B[k = ks*32 + (lane>>4)*8 + j][n = nt*16 + (lane&15)]
    const int idx = (bid-16)*256 + tid;
    int blk = idx >> 9, rem = idx & 511, lane = rem >> 3, j = rem & 7;
    int nt = blk >> 1, ks = blk & 1;
    int k = ks*32 + ((lane>>4)<<3) + j, n = nt*16 + (lane & 15);
    float v = (k < 54) ? ldT(tW0, k*64 + n) : 0.0f;
    fu[idx] = f2bu(v);
  } else if (bid < 48){
    const int idx = (bid-32)*256 + tid;
    int blk = idx >> 9, rem = idx & 511, lane = rem >> 3, j = rem & 7;
    int nt = blk >> 1, ks = blk & 1;
    int k = ks*32 + ((lane>>4)<<3) + j, n = nt*16 + (lane & 15);
    fu[4096+idx] = f2bu(ldT(tW1, k*64 + n));
    fu[8192+idx] = f2bu(ldT(tW2, k*64 + n));
  } else if (bid < 52){
    const int idx = (bid-48)*256 + tid;   // 0..1023
    int blk = idx >> 9, rem = idx & 511, lane = rem >> 3, j = rem & 7;
    int ks = blk;
    int k = ks*32 + ((lane>>4)<<3) + j, n = lane & 15;
    float v = (n < 3) ? ldT(tW3, k*3 + n) : 0.0f;
    fu[12288+idx] = f2bu(v);
  } else {
    if (tid < 64){
      wb[16+tid]  = ldT(tb0, tid);
      wb[80+tid]  = ldT(tb1, tid);
      wb[144+tid] = ldT(tb2, tid);
    }
    if (tid < 16) wb[224+tid] = (tid < 3) ? ldT(tb3, tid) : 0.0f;
    if (tid == 0) wb[OFLAG] = isf32 ? 1.0f : 0.0f;
  }
}

// ================= fused stage kernel: prep + latent-il + normals-il =========
// blocks [0,64):       prep partition (53 used)
// blocks [64,2112):    latent [16][128^3] -> bf16 [128^3][16] via LDS transpose
//                      (coalesced 8B reads AND lane-contiguous 16B stores)
// blocks [2112,4160):  normals [3][128^3] -> f32x4 [128^3], lane-contiguous 16B stores
#define STAGE_BLOCKS 4160

__global__ __launch_bounds__(256)
void stage(const void* W0,const void* b0,const void* W1,const void* b1,
           const void* W2,const void* b2,const void* W3,const void* b3,
           const void* ro,const void* rd,const void* vd,
           const void* __restrict__ latent, const void* __restrict__ normals,
           float* __restrict__ wb)
{
  __shared__ int s_f32;
  __shared__ unsigned int lds[16][512];   // 32 KB transpose staging
  const int tid = threadIdx.x;
  const int bid = blockIdx.x;
  if (tid == 0) s_f32 = 0;
  __syncthreads();
  {
    // each block independently detects fp32 vs bf16 inputs from W1's bit pattern
    const bf16* t1 = (const bf16*)W1;
    float a = fabsf(__bfloat162float(t1[2*tid]));
    float b = fabsf(__bfloat162float(t1[2*tid+1]));
    if (!(a < 100.0f) || !(b < 100.0f)) atomicOr(&s_f32, 1);
  }
  __syncthreads();
  const bool isf32 = (s_f32 != 0);

  if (bid < 64){
    if (bid < PREP_BLOCKS){
      if (isf32) fill_ws_part<float>(W0,b0,W1,b1,W2,b2,W3,b3,ro,rd,vd,wb,bid,tid,true);
      else       fill_ws_part<bf16 >(W0,b0,W1,b1,W2,b2,W3,b3,ro,rd,vd,wb,bid,tid,false);
    }
  } else if (bid < 2112){
    // ---- latent transpose: block handles 1024 voxels ----
    const int vb0 = (bid-64)*1024;
    // READ phase: lds[c][q] = channel c of voxels (vb0+2q, vb0+2q+1) packed bf16
    if (isf32){
      const float* p = (const float*)latent;
#pragma unroll
      for (int c = 0; c < 16; c++){
        f32x4 q = *(const f32x4*)&p[(size_t)c*RS3 + vb0 + 4*tid];
        lds[c][2*tid]   = pkbf(q[0], q[1]);
        lds[c][2*tid+1] = pkbf(q[2], q[3]);
      }
    } else {
      const unsigned short* p = (const unsigned short*)latent;
#pragma unroll
      for (int c = 0; c < 16; c++){
        uint2 u = *(const uint2*)&p[(size_t)c*RS3 + vb0 + 4*tid];
        lds[c][2*tid]   = u.x;
        lds[c][2*tid+1] = u.y;
      }
    }
    __syncthreads();
    // WRITE phase: 8 stores/thread, each 16B at 4B lane-stride (4KB/instr coalesced)
    // out_u[u]: voxel k=vb0+(u>>3), channels 2*(u&7), 2*(u&7)+1
    unsigned int* out_u = (unsigned int*)((char*)wb + LATIL_BYTE_OFF) + (size_t)vb0*8;
    const int cb  = (tid & 1) * 8;        // channel base (0 or 8)
    const int k2b = tid >> 2;             // voxel-pair column base
    const bool h  = ((tid >> 1) & 1);     // which half of the lds uint
#pragma unroll
    for (int s = 0; s < 8; s++){
      const int col = s*64 + k2b;
      u32x4 v;
#pragma unroll
      for (int m = 0; m < 4; m++){
        unsigned int A = lds[cb + 2*m    ][col];
        unsigned int B = lds[cb + 2*m + 1][col];
        v[m] = h ? ((A >> 16)      | (B & 0xFFFF0000u))
                 : ((A & 0xFFFFu)  | (B << 16));
      }
      *(u32x4*)&out_u[s*1024 + 4*tid] = v;
    }
  } else {
    // ---- normals: block covers 1024 voxels; stores lane-contiguous 16B ----
    f32x4* nrm_il = (f32x4*)((char*)wb + NRMIL_BYTE_OFF);
    const int nb = (bid-2112)*1024;
    if (isf32){
      const float* p = (const float*)normals;
#pragma unroll
      for (int j = 0; j < 4; j++){
        const int v = nb + j*256 + tid;
        nrm_il[v] = (f32x4){ p[v], p[(size_t)RS3+v], p[(size_t)2*RS3+v], 0.0f };
      }
    } else {
      const unsigned short* p = (const unsigned short*)normals;
#pragma unroll
      for (int j = 0; j < 4; j++){
        const int v = nb + j*256 + tid;
        nrm_il[v] = (f32x4){ bu2f(p[v]), bu2f(p[(size_t)RS3+v]),
                             bu2f(p[(size_t)2*RS3+v]), 0.0f };
      }
    }
  }
}

// standalone prep (fallback path only)
__global__ __launch_bounds__(256)
void prep(const void* W0,const void* b0,const void* W1,const void* b1,
          const void* W2,const void* b2,const void* W3,const void* b3,
          const void* ro,const void* rd,const void* vd,
          float* __restrict__ wb)
{
  __shared__ int s_f32;
  const int tid = threadIdx.x;
  const int bid = blockIdx.x;
  if (tid == 0) s_f32 = 0;
  __syncthreads();
  {
    const bf16* t1 = (const bf16*)W1;
    float a = fabsf(__bfloat162float(t1[2*tid]));
    float b = fabsf(__bfloat162float(t1[2*tid+1]));
    if (!(a < 100.0f) || !(b < 100.0f)) atomicOr(&s_f32, 1);
  }
  __syncthreads();
  const bool isf32 = (s_f32 != 0);
  if (isf32) fill_ws_part<float>(W0,b0,W1,b1,W2,b2,W3,b3,ro,rd,vd,wb,bid,tid,true);
  else       fill_ws_part<bf16 >(W0,b0,W1,b1,W2,b2,W3,b3,ro,rd,vd,wb,bid,tid,false);
}

// ---- fast render: one block/ray, thread i = sample i, interleaved grids ----
__global__ __launch_bounds__(256, 4)
void render_fast(const float* __restrict__ wb, float* __restrict__ out)
{
  const int ray  = blockIdx.x;
  const int i    = threadIdx.x;
  const int lane = i & 63;
  const int wv   = i >> 6;
  const int quad = lane >> 4;
  const int n15  = lane & 15;
  const int wbase = wv * 64;

  __shared__ unsigned short act[NSAMP*72];   // row stride 72 bf16 (144 B)
  __shared__ float sh_w[NSAMP];
  __shared__ float sh_wt[4];
  __shared__ float red[4][8];
  __shared__ float red_rgb[4][16];

  const unsigned short* lat_il = (const unsigned short*)((const char*)wb + LATIL_BYTE_OFF);
  const f32x4* nrm_il = (const f32x4*)((const char*)wb + NRMIL_BYTE_OFF);

  const float ox = wb[ORO+ray*3+0], oy = wb[ORO+ray*3+1], oz = wb[ORO+ray*3+2];
  const float dx = wb[ORD+ray*3+0], dy = wb[ORD+ray*3+1], dz = wb[ORD+ray*3+2];
  const float vx = wb[OVD+ray*3+0], vy = wb[OVD+ray*3+1], vz = wb[OVD+ray*3+2];

  const float t  = 0.2f + (2.8f/255.0f) * (float)i;
  const float px = ox + dx*t, py = oy + dy*t, pz = oz + dz*t;
  const bool inb = (px >= -1.0f) & (px <= 1.0f) & (py >= -1.0f) & (py <= 1.0f)
                 & (pz >= -1.0f) & (pz <= 1.0f);

  float alpha = 0.0f, nx = 0.0f, ny = 0.0f, nz = 0.0f;
  unsigned short* arow = &act[i*72];

  if (inb) {
    float ux = fminf(fmaxf((px+1.0f)*0.5f, 0.0f), 1.0f) * 127.0f;
    float uy = fminf(fmaxf((py+1.0f)*0.5f, 0.0f), 1.0f) * 127.0f;
    float uz = fminf(fmaxf((pz+1.0f)*0.5f, 0.0f), 1.0f) * 127.0f;
    int x0 = (int)floorf(ux); x0 = x0 > 126 ? 126 : (x0 < 0 ? 0 : x0);
    int y0 = (int)floorf(uy); y0 = y0 > 126 ? 126 : (y0 < 0 ? 0 : y0);
    int z0 = (int)floorf(uz); z0 = z0 > 126 ? 126 : (z0 < 0 ? 0 : z0);
    float fx = ux - (float)x0, fy = uy - (float)y0, fz = uz - (float)z0;
    const float gx = 1.0f - fx, gy = 1.0f - fy, gz = 1.0f - fz;

    const int vb = (x0<<14) + (y0<<7) + z0;
    const unsigned short* Lp = lat_il + ((size_t)vb<<4);
    const f32x4* Np = nrm_il + vb;

    // 16 channels as 8 packed f32x2 pairs (lets LLVM form v_pk_fma_f32)
    f32x2 ch2[8];
#pragma unroll
    for (int w = 0; w < 8; w++) ch2[w] = (f32x2){0.f, 0.f};
    float nr0 = 0.0f, nr1 = 0.0f, nr2 = 0.0f;

    const int   loff[4] = {0, 1<<18, 1<<11, (1<<18)+(1<<11)};   // ushort offsets
    const int   noff[4] = {0, 16384, 128, 16384+128};           // f32x4 offsets
    const float wxy[4]  = {gx*gy, fx*gy, gx*fy, fx*fy};

#pragma unroll
    for (int cr = 0; cr < 4; cr++){
      const unsigned short* p = Lp + loff[cr];
      SU A0, A1, B0, B1;
      A0.s = *(const short8*)(p);        // z0, ch0..7
      A1.s = *(const short8*)(p+8);      // z0, ch8..15
      B0.s = *(const short8*)(p+16);     // z1, ch0..7
      B1.s = *(const short8*)(p+24);     // z1, ch8..15
      const float wz0 = wxy[cr]*gz, wz1 = wxy[cr]*fz;
      const f32x2 w0v = (f32x2){wz0, wz0}, w1v = (f32x2){wz1, wz1};
#pragma unroll
      for (int w = 0; w < 4; w++){
        f32x2 va = (f32x2){__uint_as_float(A0.u[w] << 16), __uint_as_float(A0.u[w] & 0xFFFF0000u)};
        f32x2 vb2= (f32x2){__uint_as_float(B0.u[w] << 16), __uint_as_float(B0.u[w] & 0xFFFF0000u)};
        ch2[w] += w0v*va + w1v*vb2;
        f32x2 vc = (f32x2){__uint_as_float(A1.u[w] << 16), __uint_as_float(A1.u[w] & 0xFFFF0000u)};
        f32x2 vd = (f32x2){__uint_as_float(B1.u[w] << 16), __uint_as_float(B1.u[w] & 0xFFFF0000u)};
        ch2[w+4] += w0v*vc + w1v*vd;
      }
      f32x4 n0 = Np[noff[cr]];
      f32x4 n1 = Np[noff[cr]+1];
      nr0 += wz0*n0[0] + wz1*n1[0];
      nr1 += wz0*n0[1] + wz1*n1[1];
      nr2 += wz0*n0[2] + wz1*n1[2];
    }

    float chv[16];
#pragma unroll
    for (int w = 0; w < 8; w++){ chv[2*w] = ch2[w][0]; chv[2*w+1] = ch2[w][1]; }

    float xs = chv[0] + ACT_SHIFT;
    float sp = xs > 15.0f ? xs : log1pf(__expf(xs));
    alpha = 1.0f - __expf(-sp * 0.5f);

    float nn  = sqrtf(nr0*nr0 + nr1*nr1 + nr2*nr2);
    float ninv = 1.0f / fmaxf(nn, 1e-12f);
    nx = nr0*ninv; ny = nr1*ninv; nz = nr2*ninv;

    float dt = -(vx*nx + vy*ny + vz*nz);
    float rx = 2.0f*dt*nx + vx, ry = 2.0f*dt*ny + vy, rz = 2.0f*dt*nz + vz;

    // f=0 via sincos; f=1..5 via double-angle recurrence
    float sX[6], sY[6], sZ[6], cX[6], cY[6], cZ[6];
    __sincosf(rx, &sX[0], &cX[0]);
    __sincosf(ry, &sY[0], &cY[0]);
    __sincosf(rz, &sZ[0], &cZ[0]);
#pragma unroll
    for (int f = 1; f < 6; f++){
      sX[f] = 2.0f*sX[f-1]*cX[f-1];  cX[f] = fmaf(-2.0f*sX[f-1], sX[f-1], 1.0f);
      sY[f] = 2.0f*sY[f-1]*cY[f-1];  cY[f] = fmaf(-2.0f*sY[f-1], sY[f-1], 1.0f);
      sZ[f] = 2.0f*sZ[f-1]*cZ[f-1];  cZ[f] = fmaf(-2.0f*sZ[f-1], sZ[f-1], 1.0f);
    }

    // feat -> LDS in 16-element chunks (native converts — compiler emits hw cvt)
    short8 v0, v1;
#pragma unroll
    for (int j = 0; j < 8; j++) v0[j] = (short)f2bn(chv[1+j]);
#pragma unroll
    for (int j = 0; j < 7; j++) v1[j] = (short)f2bn(chv[9+j]);
    v1[7] = (short)f2bn(rx);
    *(short8*)&arow[0] = v0; *(short8*)&arow[8] = v1;
    v0[0]=(short)f2bn(ry);     v0[1]=(short)f2bn(rz);
    v0[2]=(short)f2bn(sX[0]);  v0[3]=(short)f2bn(sY[0]);  v0[4]=(short)f2bn(sZ[0]);
    v0[5]=(short)f2bn(sX[1]);  v0[6]=(short)f2bn(sY[1]);  v0[7]=(short)f2bn(sZ[1]);
    v1[0]=(short)f2bn(sX[2]);  v1[1]=(short)f2bn(sY[2]);  v1[2]=(short)f2bn(sZ[2]);
    v1[3]=(short)f2bn(sX[3]);  v1[4]=(short)f2bn(sY[3]);  v1[5]=(short)f2bn(sZ[3]);
    v1[6]=(short)f2bn(sX[4]);  v1[7]=(short)f2bn(sY[4]);
    *(short8*)&arow[16] = v0; *(short8*)&arow[24] = v1;
    v0[0]=(short)f2bn(sZ[4]);  v0[1]=(short)f2bn(sX[5]);
    v0[2]=(short)f2bn(sY[5]);  v0[3]=(short)f2bn(sZ[5]);
    v0[4]=(short)f2bn(cX[0]);  v0[5]=(short)f2bn(cY[0]);  v0[6]=(short)f2bn(cZ[0]);
    v0[7]=(short)f2bn(cX[1]);
    v1[0]=(short)f2bn(cY[1]);  v1[1]=(short)f2bn(cZ[1]);
    v1[2]=(short)f2bn(cX[2]);  v1[3]=(short)f2bn(cY[2]);  v1[4]=(short)f2bn(cZ[2]);
    v1[5]=(short)f2bn(cX[3]);  v1[6]=(short)f2bn(cY[3]);  v1[7]=(short)f2bn(cZ[3]);
    *(short8*)&arow[32] = v0; *(short8*)&arow[40] = v1;
    v0[0]=(short)f2bn(cX[4]);  v0[1]=(short)f2bn(cY[4]);  v0[2]=(short)f2bn(cZ[4]);
    v0[3]=(short)f2bn(cX[5]);  v0[4]=(short)f2bn(cY[5]);  v0[5]=(short)f2bn(cZ[5]);
    v0[6]=0; v0[7]=0;
#pragma unroll
    for (int j = 0; j < 8; j++) v1[j] = 0;
    *(short8*)&arow[48] = v0; *(short8*)&arow[56] = v1;
  } else {
    short8 z;
#pragma unroll
    for (int j = 0; j < 8; j++) z[j] = 0;
#pragma unroll
    for (int c = 0; c < 8; c++) *(short8*)&arow[c*8] = z;
  }

  // ---- transmittance: wave shfl scan + cross-wave prefix ----
  float xv = fmaxf(1.0f - alpha, 1e-10f);
  float incl = xv;
#pragma unroll
  for (int off = 1; off < 64; off <<= 1){
    float y = __shfl_up(incl, off, 64);
    if (lane >= off) incl *= y;
  }
  float excl = __shfl_up(incl, 1, 64);
  if (lane == 0) excl = 1.0f;
  if (lane == 63) sh_wt[wv] = incl;
  __syncthreads();   // B1

  float pre = 1.0f;
#pragma unroll
  for (int k = 0; k < 4; k++) if (k < wv) pre *= sh_wt[k];
  const float last = sh_wt[0]*sh_wt[1]*sh_wt[2]*sh_wt[3];
  const float av = pre * excl;
  const float w  = alpha * av;
  sh_w[i] = w;

  float* outw = out + 36864;            // weights      (4096*256)
  float* outa = out + 36864 + 1048576;  // alphainv_cum (4096*257)
  outw[ray*NSAMP + i] = w;
  outa[ray*(NSAMP+1) + i] = av;
  if (i == NSAMP-1) outa[ray*(NSAMP+1) + NSAMP] = last;

  {
    float vals[5] = { w*t, w, w*nx, w*ny, w*nz };
#pragma unroll
    for (int v = 0; v < 5; v++){
      float s = vals[v];
#pragma unroll
      for (int m = 32; m > 0; m >>= 1) s += __shfl_xor(s, m, 64);
      if (lane == 0) red[wv][v] = s;
    }
  }
  __syncthreads();   // B2
  if (i == 0){
    float s0 = red[0][0]+red[1][0]+red[2][0]+red[3][0];
    float s1 = red[0][1]+red[1][1]+red[2][1]+red[3][1];
    float s2 = red[0][2]+red[1][2]+red[2][2]+red[3][2];
    float s3 = red[0][3]+red[1][3]+red[2][3]+red[3][3];
    float s4 = red[0][4]+red[1][4]+red[2][4]+red[3][4];
    const float dm = s0 + last * 3.0f;
    float* o1 = out + 12288; o1[ray] = dm;
    float* o2 = out + 16384; o2[ray] = 1.0f / dm;
    float* o3 = out + 20480; o3[ray] = s1;
    float* o4 = out + 24576;
    o4[ray*3+0] = s2; o4[ray*3+1] = s3; o4[ray*3+2] = s4;
  }

  // ---- MLP via MFMA: wave handles rows [wbase, wbase+64) ----
  const short8* fr = (const short8*)((const char*)wb + FRAG_BYTE_OFF);

#pragma unroll
  for (int l = 0; l < 3; l++){
    const int fbase = l * 512;
    f32x4 acc[4][4];
#pragma unroll
    for (int mt = 0; mt < 4; mt++)
#pragma unroll
      for (int nt = 0; nt < 4; nt++) acc[mt][nt] = (f32x4){0.f,0.f,0.f,0.f};

#pragma unroll
    for (int ks = 0; ks < 2; ks++){
      short8 a[4], b[4];
#pragma unroll
      for (int mt = 0; mt < 4; mt++)
        a[mt] = *(const short8*)&act[(wbase + mt*16 + n15)*72 + ks*32 + quad*8];
#pragma unroll
      for (int nt = 0; nt < 4; nt++)
        b[nt] = fr[fbase + (nt*2+ks)*64 + lane];
#pragma unroll
      for (int mt = 0; mt < 4; mt++)
#pragma unroll
        for (int nt = 0; nt < 4; nt++)
          acc[mt][nt] = __builtin_amdgcn_mfma_f32_16x16x32_bf16(a[mt], b[nt], acc[mt][nt], 0, 0, 0);
    }
    __syncthreads();
#pragma unroll
    for (int nt = 0; nt < 4; nt++){
      const float bn = wb[OBIAS + l*64 + nt*16 + n15];
#pragma unroll
      for (int mt = 0; mt < 4; mt++){
#pragma unroll
        for (int r = 0; r < 4; r++){
          float vv = fmaxf(acc[mt][nt][r] + bn, 0.0f);
          act[(wbase + mt*16 + quad*4 + r)*72 + nt*16 + n15] = f2bn(vv);
        }
      }
    }
    __syncthreads();
  }

  // layer 3 + fused weighted rgb reduction
  {
    f32x4 acc3[4];
#pragma unroll
    for (int mt = 0; mt < 4; mt++) acc3[mt] = (f32x4){0.f,0.f,0.f,0.f};
#pragma unroll
    for (int ks = 0; ks < 2; ks++){
      short8 a[4];
#pragma unroll
      for (int mt = 0; mt < 4; mt++)
        a[mt] = *(const short8*)&act[(wbase + mt*16 + n15)*72 + ks*32 + quad*8];
      short8 b = fr[1536 + ks*64 + lane];
#pragma unroll
      for (int mt = 0; mt < 4; mt++)
        acc3[mt] = __builtin_amdgcn_mfma_f32_16x16x32_bf16(a[mt], b, acc3[mt], 0, 0, 0);
    }
    const float bn3 = wb[OBIAS + 208 + n15];
    float p = 0.0f;
#pragma unroll
    for (int mt = 0; mt < 4; mt++){
#pragma unroll
      for (int r = 0; r < 4; r++){
        const float wr = sh_w[wbase + mt*16 + quad*4 + r];
        const float logit = acc3[mt][r] + bn3;
        p += wr * (1.0f / (1.0f + __expf(-logit)));
      }
    }
    p += __shfl_xor(p, 16, 64);
    p += __shfl_xor(p, 32, 64);
    if (lane < 16) red_rgb[wv][lane] = p;
  }
  __syncthreads();   // B3
  if (i < 3){
    float s = red_rgb[0][i] + red_rgb[1][i] + red_rgb[2][i] + red_rgb[3][i];
    out[ray*3+i] = s + last;   // + BG*last, BG=1
  }
}

// ================= fallback path (ws too small) =================
template<typename GT>
__device__ __forceinline__ void render_body(const GT* __restrict__ latent,
                                            const GT* __restrict__ normals,
                                            const float* __restrict__ wb,
                                            float* __restrict__ out)
{
  const int ray  = blockIdx.x;
  const int i    = threadIdx.x;
  const int lane = i & 63;
  const int wv   = i >> 6;
  const int quad = lane >> 4;
  const int n15  = lane & 15;
  const int wbase = wv * 64;

  __shared__ unsigned short act[NSAMP*72];
  __shared__ float sh_w[NSAMP];
  __shared__ float sh_wt[4];
  __shared__ float red[4][8];
  __shared__ float red_rgb[4][16];

  const float ox = wb[ORO+ray*3+0], oy = wb[ORO+ray*3+1], oz = wb[ORO+ray*3+2];
  const float dx = wb[ORD+ray*3+0], dy = wb[ORD+ray*3+1], dz = wb[ORD+ray*3+2];
  const float vx = wb[OVD+ray*3+0], vy = wb[OVD+ray*3+1], vz = wb[OVD+ray*3+2];

  const float t  = 0.2f + (2.8f/255.0f) * (float)i;
  const float px = ox + dx*t, py = oy + dy*t, pz = oz + dz*t;
  const bool inb = (px >= -1.0f) & (px <= 1.0f) & (py >= -1.0f) & (py <= 1.0f)
                 & (pz >= -1.0f) & (pz <= 1.0f);

  float alpha = 0.0f, nx = 0.0f, ny = 0.0f, nz = 0.0f;
  float fv[64];
#pragma unroll
  for (int k = 0; k < 64; k++) fv[k] = 0.0f;

  if (inb) {
    float ux = fminf(fmaxf((px+1.0f)*0.5f, 0.0f), 1.0f) * 127.0f;
    float uy = fminf(fmaxf((py+1.0f)*0.5f, 0.0f), 1.0f) * 127.0f;
    float uz = fminf(fmaxf((pz+1.0f)*0.5f, 0.0f), 1.0f) * 127.0f;
    int x0 = (int)floorf(ux); x0 = x0 > 126 ? 126 : (x0 < 0 ? 0 : x0);
    int y0 = (int)floorf(uy); y0 = y0 > 126 ? 126 : (y0 < 0 ? 0 : y0);
    int z0 = (int)floorf(uz); z0 = z0 > 126 ? 126 : (z0 < 0 ? 0 : z0);
    float fx = ux - (float)x0, fy = uy - (float)y0, fz = uz - (float)z0;
    const int base = x0*RS2 + y0*RESG + z0;
    const float gx = 1.0f - fx, gy = 1.0f - fy, gz = 1.0f - fz;
    const float w000 = gx*gy*gz, w100 = fx*gy*gz, w010 = gx*fy*gz, w001 = gx*gy*fz;
    const float w110 = fx*fy*gz, w101 = fx*gy*fz, w011 = gx*fy*fz, w111 = fx*fy*fz;

    float ch[19];
#pragma unroll
    for (int c = 0; c < 19; c++){
      const GT* g = (c < 16 ? latent + c*RS3 : normals + (c-16)*RS3) + base;
      ch[c] = w000*ldT(g,0)        + w100*ldT(g,RS2)
            + w010*ldT(g,RESG)     + w001*ldT(g,1)
            + w110*ldT(g,RS2+RESG) + w101*ldT(g,RS2+1)
            + w011*ldT(g,RESG+1)   + w111*ldT(g,RS2+RESG+1);
    }

    float xs = ch[0] + ACT_SHIFT;
    float sp = xs > 15.0f ? xs : log1pf(__expf(xs));
    alpha = 1.0f - __expf(-sp * 0.5f);

    float nn  = sqrtf(ch[16]*ch[16] + ch[17]*ch[17] + ch[18]*ch[18]);
    float ninv = 1.0f / fmaxf(nn, 1e-12f);
    nx = ch[16]*ninv; ny = ch[17]*ninv; nz = ch[18]*ninv;

    float dt = -(vx*nx + vy*ny + vz*nz);
    float rx = 2.0f*dt*nx + vx, ry = 2.0f*dt*ny + vy, rz = 2.0f*dt*nz + vz;

#pragma unroll
    for (int k = 0; k < 15; k++) fv[k] = ch[k+1];
    fv[15] = rx; fv[16] = ry; fv[17] = rz;
#pragma unroll
    for (int f = 0; f < 6; f++){
      float s = (float)(1 << f);
      fv[18 + f*3 + 0] = __sinf(rx*s);
      fv[18 + f*3 + 1] = __sinf(ry*s);
      fv[18 + f*3 + 2] = __sinf(rz*s);
      fv[36 + f*3 + 0] = __cosf(rx*s);
      fv[36 + f*3 + 1] = __cosf(ry*s);
      fv[36 + f*3 + 2] = __cosf(rz*s);
    }
  }

#pragma unroll
  for (int c = 0; c < 8; c++){
    short8 v;
#pragma unroll
    for (int k = 0; k < 8; k++) v[k] = (short)f2bu(fv[c*8+k]);
    *(short8*)&act[i*72 + c*8] = v;
  }

  float xvv = fmaxf(1.0f - alpha, 1e-10f);
  float incl = xvv;
#pragma unroll
  for (int off = 1; off < 64; off <<= 1){
    float y = __shfl_up(incl, off, 64);
    if (lane >= off) incl *= y;
  }
  float excl = __shfl_up(incl, 1, 64);
  if (lane == 0) excl = 1.0f;
  if (lane == 63) sh_wt[wv] = incl;
  __syncthreads();

  float pre = 1.0f;
#pragma unroll
  for (int k = 0; k < 4; k++) if (k < wv) pre *= sh_wt[k];
  const float last = sh_wt[0]*sh_wt[1]*sh_wt[2]*sh_wt[3];
  const float av = pre * excl;
  const float w  = alpha * av;
  sh_w[i] = w;

  float* outw = out + 36864;
  float* outa = out + 36864 + 1048576;
  outw[ray*NSAMP + i] = w;
  outa[ray*(NSAMP+1) + i] = av;
  if (i == NSAMP-1) outa[ray*(NSAMP+1) + NSAMP] = last;

  {
    float vals[5] = { w*t, w, w*nx, w*ny, w*nz };
#pragma unroll
    for (int v = 0; v < 5; v++){
      float s = vals[v];
#pragma unroll
      for (int m = 32; m > 0; m >>= 1) s += __shfl_xor(s, m, 64);
      if (lane == 0) red[wv][v] = s;
    }
  }
  __syncthreads();
  if (i == 0){
    float s0 = red[0][0]+red[1][0]+red[2][0]+red[3][0];
    float s1 = red[0][1]+red[1][1]+red[2][1]+red[3][1];
    float s2 = red[0][2]+red[1][2]+red[2][2]+red[3][2];
    float s3 = red[0][3]+red[1][3]+red[2][3]+red[3][3];
    float s4 = red[0][4]+red[1][4]+red[2][4]+red[3][4];
    const float dm = s0 + last * 3.0f;
    float* o1 = out + 12288; o1[ray] = dm;
    float* o2 = out + 16384; o2[ray] = 1.0f / dm;
    float* o3 = out + 20480; o3[ray] = s1;
    float* o4 = out + 24576;
    o4[ray*3+0] = s2; o4[ray*3+1] = s3; o4[ray*3+2] = s4;
  }

  const short8* fr = (const short8*)((const char*)wb + FRAG_BYTE_OFF);

#pragma unroll
  for (int l = 0; l < 3; l++){
    const int fbase = l * 512;
    f32x4 acc[4][4];
#pragma unroll
    for (int mt = 0; mt < 4; mt++)
#pragma unroll
      for (int nt = 0; nt < 4; nt++) acc[mt][nt] = (f32x4){0.f,0.f,0.f,0.f};

#pragma unroll
    for (int ks = 0; ks < 2; ks++){
      short8 a[4], b[4];
#pragma unroll
      for (int mt = 0; mt < 4; mt++)
        a[mt] = *(const short8*)&act[(wbase + mt*16 + n15)*72 + ks*32 + quad*8];
#pragma unroll
      for (int nt = 0; nt < 4; nt++)
        b[nt] = fr[fbase + (nt*2+ks)*64 + lane];
#pragma unroll
      for (int mt = 0; mt < 4; mt++)
#pragma unroll
        for (int nt = 0; nt < 4; nt++)
          acc[mt][nt] = __builtin_amdgcn_mfma_f32_16x16x32_bf16(a[mt], b[nt], acc[mt][nt], 0, 0, 0);
    }
    __syncthreads();
#pragma unroll
    for (int nt = 0; nt < 4; nt++){
      const float bn = wb[OBIAS + l*64 + nt*16 + n15];
#pragma unroll
      for (int mt = 0; mt < 4; mt++){
#pragma unroll
        for (int r = 0; r < 4; r++){
          float vv = fmaxf(acc[mt][nt][r] + bn, 0.0f);
          act[(wbase + mt*16 + quad*4 + r)*72 + nt*16 + n15] = f2bu(vv);
        }
      }
    }
    __syncthreads();
  }

  {
    f32x4 acc3[4];
#pragma unroll
    for (int mt = 0; mt < 4; mt++) acc3[mt] = (f32x4){0.f,0.f,0.f,0.f};
#pragma unroll
    for (int ks = 0; ks < 2; ks++){
      short8 a[4];
#pragma unroll
      for (int mt = 0; mt < 4; mt++)
        a[mt] = *(const short8*)&act[(wbase + mt*16 + n15)*72 + ks*32 + quad*8];
      short8 b = fr[1536 + ks*64 + lane];
#pragma unroll
      for (int mt = 0; mt < 4; mt++)
        acc3[mt] = __builtin_amdgcn_mfma_f32_16x16x32_bf16(a[mt], b, acc3[mt], 0, 0, 0);
    }
    const float bn3 = wb[OBIAS + 208 + n15];
    float p = 0.0f;
#pragma unroll
    for (int mt = 0; mt < 4; mt++){
#pragma unroll
      for (int r = 0; r < 4; r++){
        const float wr = sh_w[wbase + mt*16 + quad*4 + r];
        const float logit = acc3[mt][r] + bn3;
        p += wr * (1.0f / (1.0f + __expf(-logit)));
      }
    }
    p += __shfl_xor(p, 16, 64);
    p += __shfl_xor(p, 32, 64);
    if (lane < 16) red_rgb[wv][lane] = p;
  }
  __syncthreads();
  if (i < 3){
    float s = red_rgb[0][i] + red_rgb[1][i] + red_rgb[2][i] + red_rgb[3][i];
    out[ray*3+i] = s + last;
  }
}

__global__ __launch_bounds__(256)
void render_fallback(const void* __restrict__ latent, const void* __restrict__ normals,
                     const float* __restrict__ wb, float* __restrict__ out)
{
  if (wb[OFLAG] > 0.5f)
    render_body<float>((const float*)latent, (const float*)normals, wb, out);
  else
    render_body<bf16 >((const bf16*)latent,  (const bf16*)normals,  wb, out);
}

extern "C" void kernel_launch(void* const* d_in, const int* in_sizes, int n_in,
                              void* d_out, int out_size, void* d_ws, size_t ws_size,
                              hipStream_t stream)
{
  float* wb = (float*)d_ws;
  if (ws_size >= WS_NEED){
    stage<<<STAGE_BLOCKS, 256, 0, stream>>>(d_in[5], d_in[6], d_in[7], d_in[8],
                                            d_in[9], d_in[10], d_in[11], d_in[12],
                                            d_in[0], d_in[1], d_in[2],
                                            d_in[3], d_in[4], wb);
    render_fast<<<NRAYS, 256, 0, stream>>>(wb, (float*)d_out);
  } else {
    prep<<<PREP_BLOCKS, 256, 0, stream>>>(d_in[5], d_in[6], d_in[7], d_in[8],
                                          d_in[9], d_in[10], d_in[11], d_in[12],
                                          d_in[0], d_in[1], d_in[2], wb);
    render_fallback<<<NRAYS, 256, 0, stream>>>(d_in[3], d_in[4], wb, (float*)d_out);
  }
}

// Round 8
// 328.266 us; speedup vs baseline: 1.0340x; 1.0163x over previous
//
#include <hip/hip_runtime.h>
#include <hip/hip_bf16.h>
#include <math.h>

typedef __hip_bfloat16 bf16;
typedef float f32x4 __attribute__((ext_vector_type(4)));
typedef float f32x2 __attribute__((ext_vector_type(2)));
typedef short short8 __attribute__((ext_vector_type(8)));
typedef short short4v __attribute__((ext_vector_type(4)));
typedef unsigned int u32x4 __attribute__((ext_vector_type(4)));

#define NRAYS 4096
#define NSAMP 256
#define RESG  128
#define RS2   16384      // 128*128 (x stride)
#define RS3   2097152    // 128^3   (channel stride)
#define ACT_SHIFT (-4.59511985013459f)

// ---- ws layout ----
#define OFLAG 0
#define OBIAS 16        // b0@16, b1@80, b2@144, b3(16 padded)@224
#define ORO   272       // rays_o fp32 [4096*3]
#define ORD   12560     // rays_d normalized
#define OVD   24848     // viewdirs normalized
#define FRAG_BYTE_OFF 148544
#define LATIL_BYTE_OFF 1048576ULL            // ushort [128^3][16]  (67.1 MB)
// normals region: bf16 path = ushort4 [128^3] (16.8 MB, lossless vs bf16 input)
//                 f32 path  = f32x4  [128^3] (33.5 MB) — same base offset
#define NRMIL_BYTE_OFF 68157440ULL
#define WS_NEED        101711872ULL

__device__ __forceinline__ float ldT(const float* p, size_t i){ return p[i]; }
__device__ __forceinline__ float ldT(const bf16*  p, size_t i){ return __bfloat162float(p[i]); }

// RNE float->bf16 bits (manual bit math; cold/fallback paths)
__device__ __forceinline__ unsigned short f2bu(float f){
  unsigned int x = __float_as_uint(f);
  unsigned int r = (x + 0x7FFFu + ((x >> 16) & 1u)) >> 16;
  return (unsigned short)r;
}
// native RNE convert — compiler lowers to hw v_cvt (schedulable, unlike asm)
__device__ __forceinline__ unsigned short f2bn(float f){
  union { __hip_bfloat16 h; unsigned short u; } cv;
  cv.h = __float2bfloat16(f);
  return cv.u;
}
__device__ __forceinline__ float bu2f(short s){
  return __uint_as_float(((unsigned int)(unsigned short)s) << 16);
}
// HW packed RNE f32->bf16 (memory-bound stage kernel only)
__device__ __forceinline__ unsigned int pkbf(float lo, float hi){
  unsigned int r;
  asm("v_cvt_pk_bf16_f32 %0, %1, %2" : "=v"(r) : "v"(lo), "v"(hi));
  return r;
}
union SU { short8 s; unsigned int u[4]; };

// prep work partition (bid within [0,53)):
#define PREP_BLOCKS 53

template<typename T>
__device__ void fill_ws_part(const void* W0,const void* b0,const void* W1,const void* b1,
                             const void* W2,const void* b2,const void* W3,const void* b3,
                             const void* ro,const void* rd,const void* vd,
                             float* __restrict__ wb, int bid, int tid, bool isf32)
{
  const T* tW0=(const T*)W0; const T* tb0=(const T*)b0;
  const T* tW1=(const T*)W1; const T* tb1=(const T*)b1;
  const T* tW2=(const T*)W2; const T* tb2=(const T*)b2;
  const T* tW3=(const T*)W3; const T* tb3=(const T*)b3;
  const T* tro=(const T*)ro; const T* trd=(const T*)rd; const T* tvd=(const T*)vd;

  unsigned short* fu = (unsigned short*)((char*)wb + FRAG_BYTE_OFF);

  if (bid < 16){
    const int r = bid*256 + tid;
    float ox = ldT(tro, r*3+0), oy = ldT(tro, r*3+1), oz = ldT(tro, r*3+2);
    wb[ORO+r*3+0]=ox; wb[ORO+r*3+1]=oy; wb[ORO+r*3+2]=oz;
    float dx = ldT(trd, r*3+0), dy = ldT(trd, r*3+1), dz = ldT(trd, r*3+2);
    float dn = 1.0f / sqrtf(dx*dx+dy*dy+dz*dz);
    wb[ORD+r*3+0]=dx*dn; wb[ORD+r*3+1]=dy*dn; wb[ORD+r*3+2]=dz*dn;
    float vx = ldT(tvd, r*3+0), vy = ldT(tvd, r*3+1), vz = ldT(tvd, r*3+2);
    float vn = 1.0f / sqrtf(vx*vx+vy*vy+vz*vz);
    wb[OVD+r*3+0]=vx*vn; wb[OVD+r*3+1]=vy*vn; wb[OVD+r*3+2]=vz*vn;
  } else if (bid < 32){
    // mfma_f32_16x16x32_bf16 B layout:
    //   lane holds B[k = ks*32 + (lane>>4)*8 + j][n = nt*16 + (lane&15)]
    const int idx = (bid-16)*256 + tid;
    int blk = idx >> 9, rem = idx & 511, lane = rem >> 3, j = rem & 7;
    int nt = blk >> 1, ks = blk & 1;
    int k = ks*32 + ((lane>>4)<<3) + j, n = nt*16 + (lane & 15);
    float v = (k < 54) ? ldT(tW0, k*64 + n) : 0.0f;
    fu[idx] = f2bu(v);
  } else if (bid < 48){
    const int idx = (bid-32)*256 + tid;
    int blk = idx >> 9, rem = idx & 511, lane = rem >> 3, j = rem & 7;
    int nt = blk >> 1, ks = blk & 1;
    int k = ks*32 + ((lane>>4)<<3) + j, n = nt*16 + (lane & 15);
    fu[4096+idx] = f2bu(ldT(tW1, k*64 + n));
    fu[8192+idx] = f2bu(ldT(tW2, k*64 + n));
  } else if (bid < 52){
    const int idx = (bid-48)*256 + tid;   // 0..1023
    int blk = idx >> 9, rem = idx & 511, lane = rem >> 3, j = rem & 7;
    int ks = blk;
    int k = ks*32 + ((lane>>4)<<3) + j, n = lane & 15;
    float v = (n < 3) ? ldT(tW3, k*3 + n) : 0.0f;
    fu[12288+idx] = f2bu(v);
  } else {
    if (tid < 64){
      wb[16+tid]  = ldT(tb0, tid);
      wb[80+tid]  = ldT(tb1, tid);
      wb[144+tid] = ldT(tb2, tid);
    }
    if (tid < 16) wb[224+tid] = (tid < 3) ? ldT(tb3, tid) : 0.0f;
    if (tid == 0) wb[OFLAG] = isf32 ? 1.0f : 0.0f;
  }
}

// ================= fused stage kernel: prep + latent-il + normals-il =========
// blocks [0,64):       prep partition (53 used)
// blocks [64,2112):    latent [16][128^3] -> bf16 [128^3][16] via LDS transpose
// blocks [2112,4160):  normals [3][128^3] -> bf16x4 [128^3] (8 B/voxel, lossless)
//                      (f32-input path keeps f32x4 records)
#define STAGE_BLOCKS 4160

__global__ __launch_bounds__(256)
void stage(const void* W0,const void* b0,const void* W1,const void* b1,
           const void* W2,const void* b2,const void* W3,const void* b3,
           const void* ro,const void* rd,const void* vd,
           const void* __restrict__ latent, const void* __restrict__ normals,
           float* __restrict__ wb)
{
  __shared__ int s_f32;
  __shared__ unsigned int lds[16][512];   // 32 KB transpose staging
  const int tid = threadIdx.x;
  const int bid = blockIdx.x;
  if (tid == 0) s_f32 = 0;
  __syncthreads();
  {
    // each block independently detects fp32 vs bf16 inputs from W1's bit pattern
    const bf16* t1 = (const bf16*)W1;
    float a = fabsf(__bfloat162float(t1[2*tid]));
    float b = fabsf(__bfloat162float(t1[2*tid+1]));
    if (!(a < 100.0f) || !(b < 100.0f)) atomicOr(&s_f32, 1);
  }
  __syncthreads();
  const bool isf32 = (s_f32 != 0);

  if (bid < 64){
    if (bid < PREP_BLOCKS){
      if (isf32) fill_ws_part<float>(W0,b0,W1,b1,W2,b2,W3,b3,ro,rd,vd,wb,bid,tid,true);
      else       fill_ws_part<bf16 >(W0,b0,W1,b1,W2,b2,W3,b3,ro,rd,vd,wb,bid,tid,false);
    }
  } else if (bid < 2112){
    // ---- latent transpose: block handles 1024 voxels ----
    const int vb0 = (bid-64)*1024;
    // READ phase: lds[c][q] = channel c of voxels (vb0+2q, vb0+2q+1) packed bf16
    if (isf32){
      const float* p = (const float*)latent;
#pragma unroll
      for (int c = 0; c < 16; c++){
        f32x4 q = *(const f32x4*)&p[(size_t)c*RS3 + vb0 + 4*tid];
        lds[c][2*tid]   = pkbf(q[0], q[1]);
        lds[c][2*tid+1] = pkbf(q[2], q[3]);
      }
    } else {
      const unsigned short* p = (const unsigned short*)latent;
#pragma unroll
      for (int c = 0; c < 16; c++){
        uint2 u = *(const uint2*)&p[(size_t)c*RS3 + vb0 + 4*tid];
        lds[c][2*tid]   = u.x;
        lds[c][2*tid+1] = u.y;
      }
    }
    __syncthreads();
    // WRITE phase: 8 stores/thread, each 16B at 4B lane-stride (4KB/instr coalesced)
    unsigned int* out_u = (unsigned int*)((char*)wb + LATIL_BYTE_OFF) + (size_t)vb0*8;
    const int cb  = (tid & 1) * 8;        // channel base (0 or 8)
    const int k2b = tid >> 2;             // voxel-pair column base
    const bool h  = ((tid >> 1) & 1);     // which half of the lds uint
#pragma unroll
    for (int s = 0; s < 8; s++){
      const int col = s*64 + k2b;
      u32x4 v;
#pragma unroll
      for (int m = 0; m < 4; m++){
        unsigned int A = lds[cb + 2*m    ][col];
        unsigned int B = lds[cb + 2*m + 1][col];
        v[m] = h ? ((A >> 16)      | (B & 0xFFFF0000u))
                 : ((A & 0xFFFFu)  | (B << 16));
      }
      *(u32x4*)&out_u[s*1024 + 4*tid] = v;
    }
  } else {
    // ---- normals: block covers 1024 voxels ----
    const int nb = (bid-2112)*1024;
    if (isf32){
      f32x4* nrm_il = (f32x4*)((char*)wb + NRMIL_BYTE_OFF);
      const float* p = (const float*)normals;
#pragma unroll
      for (int j = 0; j < 4; j++){
        const int v = nb + j*256 + tid;
        nrm_il[v] = (f32x4){ p[v], p[(size_t)RS3+v], p[(size_t)2*RS3+v], 0.0f };
      }
    } else {
      // bf16x4 records {x,y,z,pad}: 4 voxels/thread, 8B reads + 32B contiguous store
      const unsigned short* p = (const unsigned short*)normals;
      const int v0 = nb + 4*tid;
      uint2 a = *(const uint2*)&p[v0];
      uint2 b = *(const uint2*)&p[(size_t)RS3 + v0];
      uint2 c = *(const uint2*)&p[(size_t)2*RS3 + v0];
      unsigned int* out_u = (unsigned int*)((char*)wb + NRMIL_BYTE_OFF) + (size_t)v0*2;
      u32x4 w0, w1;
      w0[0] = (a.x & 0xFFFFu) | (b.x << 16);   // vox v0:   x | y<<16
      w0[1] = (c.x & 0xFFFFu);                 //           z
      w0[2] = (a.x >> 16) | (b.x & 0xFFFF0000u); // vox v0+1
      w0[3] = (c.x >> 16);
      w1[0] = (a.y & 0xFFFFu) | (b.y << 16);   // vox v0+2
      w1[1] = (c.y & 0xFFFFu);
      w1[2] = (a.y >> 16) | (b.y & 0xFFFF0000u); // vox v0+3
      w1[3] = (c.y >> 16);
      *(u32x4*)&out_u[0] = w0;
      *(u32x4*)&out_u[4] = w1;
    }
  }
}

// standalone prep (fallback path only)
__global__ __launch_bounds__(256)
void prep(const void* W0,const void* b0,const void* W1,const void* b1,
          const void* W2,const void* b2,const void* W3,const void* b3,
          const void* ro,const void* rd,const void* vd,
          float* __restrict__ wb)
{
  __shared__ int s_f32;
  const int tid = threadIdx.x;
  const int bid = blockIdx.x;
  if (tid == 0) s_f32 = 0;
  __syncthreads();
  {
    const bf16* t1 = (const bf16*)W1;
    float a = fabsf(__bfloat162float(t1[2*tid]));
    float b = fabsf(__bfloat162float(t1[2*tid+1]));
    if (!(a < 100.0f) || !(b < 100.0f)) atomicOr(&s_f32, 1);
  }
  __syncthreads();
  const bool isf32 = (s_f32 != 0);
  if (isf32) fill_ws_part<float>(W0,b0,W1,b1,W2,b2,W3,b3,ro,rd,vd,wb,bid,tid,true);
  else       fill_ws_part<bf16 >(W0,b0,W1,b1,W2,b2,W3,b3,ro,rd,vd,wb,bid,tid,false);
}

// ---- fast render: one block/ray, thread i = sample i, interleaved grids ----
__global__ __launch_bounds__(256, 4)
void render_fast(const float* __restrict__ wb, float* __restrict__ out)
{
  const int ray  = blockIdx.x;
  const int i    = threadIdx.x;
  const int lane = i & 63;
  const int wv   = i >> 6;
  const int quad = lane >> 4;
  const int n15  = lane & 15;
  const int wbase = wv * 64;

  __shared__ unsigned short act[NSAMP*72];   // row stride 72 bf16 (144 B)
  __shared__ float sh_w[NSAMP];
  __shared__ float sh_wt[4];
  __shared__ float red[4][8];
  __shared__ float red_rgb[4][16];

  const unsigned short* lat_il = (const unsigned short*)((const char*)wb + LATIL_BYTE_OFF);
  const bool nf32 = (wb[OFLAG] > 0.5f);
  const f32x4* nrm_il = (const f32x4*)((const char*)wb + NRMIL_BYTE_OFF);
  const uint2* nrm_b  = (const uint2*)((const char*)wb + NRMIL_BYTE_OFF);

  const float ox = wb[ORO+ray*3+0], oy = wb[ORO+ray*3+1], oz = wb[ORO+ray*3+2];
  const float dx = wb[ORD+ray*3+0], dy = wb[ORD+ray*3+1], dz = wb[ORD+ray*3+2];
  const float vx = wb[OVD+ray*3+0], vy = wb[OVD+ray*3+1], vz = wb[OVD+ray*3+2];

  const float t  = 0.2f + (2.8f/255.0f) * (float)i;
  const float px = ox + dx*t, py = oy + dy*t, pz = oz + dz*t;
  const bool inb = (px >= -1.0f) & (px <= 1.0f) & (py >= -1.0f) & (py <= 1.0f)
                 & (pz >= -1.0f) & (pz <= 1.0f);

  float alpha = 0.0f, nx = 0.0f, ny = 0.0f, nz = 0.0f;
  unsigned short* arow = &act[i*72];

  if (inb) {
    float ux = fminf(fmaxf((px+1.0f)*0.5f, 0.0f), 1.0f) * 127.0f;
    float uy = fminf(fmaxf((py+1.0f)*0.5f, 0.0f), 1.0f) * 127.0f;
    float uz = fminf(fmaxf((pz+1.0f)*0.5f, 0.0f), 1.0f) * 127.0f;
    int x0 = (int)floorf(ux); x0 = x0 > 126 ? 126 : (x0 < 0 ? 0 : x0);
    int y0 = (int)floorf(uy); y0 = y0 > 126 ? 126 : (y0 < 0 ? 0 : y0);
    int z0 = (int)floorf(uz); z0 = z0 > 126 ? 126 : (z0 < 0 ? 0 : z0);
    float fx = ux - (float)x0, fy = uy - (float)y0, fz = uz - (float)z0;
    const float gx = 1.0f - fx, gy = 1.0f - fy, gz = 1.0f - fz;

    const int vb = (x0<<14) + (y0<<7) + z0;
    const unsigned short* Lp = lat_il + ((size_t)vb<<4);
    const f32x4* Np  = nrm_il + vb;
    const uint2* NpB = nrm_b  + vb;

    // 16 channels as 8 packed f32x2 pairs (lets LLVM form v_pk_fma_f32)
    f32x2 ch2[8];
#pragma unroll
    for (int w = 0; w < 8; w++) ch2[w] = (f32x2){0.f, 0.f};
    float nr0 = 0.0f, nr1 = 0.0f, nr2 = 0.0f;

    const int   loff[4] = {0, 1<<18, 1<<11, (1<<18)+(1<<11)};   // ushort offsets
    const int   noff[4] = {0, 16384, 128, 16384+128};           // voxel offsets
    const float wxy[4]  = {gx*gy, fx*gy, gx*fy, fx*fy};

#pragma unroll
    for (int cr = 0; cr < 4; cr++){
      const unsigned short* p = Lp + loff[cr];
      SU A0, A1, B0, B1;
      A0.s = *(const short8*)(p);        // z0, ch0..7
      A1.s = *(const short8*)(p+8);      // z0, ch8..15
      B0.s = *(const short8*)(p+16);     // z1, ch0..7
      B1.s = *(const short8*)(p+24);     // z1, ch8..15
      const float wz0 = wxy[cr]*gz, wz1 = wxy[cr]*fz;
      const f32x2 w0v = (f32x2){wz0, wz0}, w1v = (f32x2){wz1, wz1};
#pragma unroll
      for (int w = 0; w < 4; w++){
        f32x2 va = (f32x2){__uint_as_float(A0.u[w] << 16), __uint_as_float(A0.u[w] & 0xFFFF0000u)};
        f32x2 vb2= (f32x2){__uint_as_float(B0.u[w] << 16), __uint_as_float(B0.u[w] & 0xFFFF0000u)};
        ch2[w] += w0v*va + w1v*vb2;
        f32x2 vc = (f32x2){__uint_as_float(A1.u[w] << 16), __uint_as_float(A1.u[w] & 0xFFFF0000u)};
        f32x2 vd = (f32x2){__uint_as_float(B1.u[w] << 16), __uint_as_float(B1.u[w] & 0xFFFF0000u)};
        ch2[w+4] += w0v*vc + w1v*vd;
      }
      if (nf32){
        f32x4 n0 = Np[noff[cr]];
        f32x4 n1 = Np[noff[cr]+1];
        nr0 += wz0*n0[0] + wz1*n1[0];
        nr1 += wz0*n0[1] + wz1*n1[1];
        nr2 += wz0*n0[2] + wz1*n1[2];
      } else {
        uint2 qa = NpB[noff[cr]];       // vox z0: {x|y<<16, z}
        uint2 qb = NpB[noff[cr]+1];     // vox z1
        nr0 += wz0*__uint_as_float(qa.x << 16)        + wz1*__uint_as_float(qb.x << 16);
        nr1 += wz0*__uint_as_float(qa.x & 0xFFFF0000u)+ wz1*__uint_as_float(qb.x & 0xFFFF0000u);
        nr2 += wz0*__uint_as_float(qa.y << 16)        + wz1*__uint_as_float(qb.y << 16);
      }
    }

    float chv[16];
#pragma unroll
    for (int w = 0; w < 8; w++){ chv[2*w] = ch2[w][0]; chv[2*w+1] = ch2[w][1]; }

    float xs = chv[0] + ACT_SHIFT;
    float sp = xs > 15.0f ? xs : log1pf(__expf(xs));
    alpha = 1.0f - __expf(-sp * 0.5f);

    float nn  = sqrtf(nr0*nr0 + nr1*nr1 + nr2*nr2);
    float ninv = 1.0f / fmaxf(nn, 1e-12f);
    nx = nr0*ninv; ny = nr1*ninv; nz = nr2*ninv;

    float dt = -(vx*nx + vy*ny + vz*nz);
    float rx = 2.0f*dt*nx + vx, ry = 2.0f*dt*ny + vy, rz = 2.0f*dt*nz + vz;

    // f=0 via sincos; f=1..5 via double-angle recurrence
    float sX[6], sY[6], sZ[6], cX[6], cY[6], cZ[6];
    __sincosf(rx, &sX[0], &cX[0]);
    __sincosf(ry, &sY[0], &cY[0]);
    __sincosf(rz, &sZ[0], &cZ[0]);
#pragma unroll
    for (int f = 1; f < 6; f++){
      sX[f] = 2.0f*sX[f-1]*cX[f-1];  cX[f] = fmaf(-2.0f*sX[f-1], sX[f-1], 1.0f);
      sY[f] = 2.0f*sY[f-1]*cY[f-1];  cY[f] = fmaf(-2.0f*sY[f-1], sY[f-1], 1.0f);
      sZ[f] = 2.0f*sZ[f-1]*cZ[f-1];  cZ[f] = fmaf(-2.0f*sZ[f-1], sZ[f-1], 1.0f);
    }

    // feat -> LDS in 16-element chunks (native converts — compiler emits hw cvt)
    short8 v0, v1;
#pragma unroll
    for (int j = 0; j < 8; j++) v0[j] = (short)f2bn(chv[1+j]);
#pragma unroll
    for (int j = 0; j < 7; j++) v1[j] = (short)f2bn(chv[9+j]);
    v1[7] = (short)f2bn(rx);
    *(short8*)&arow[0] = v0; *(short8*)&arow[8] = v1;
    v0[0]=(short)f2bn(ry);     v0[1]=(short)f2bn(rz);
    v0[2]=(short)f2bn(sX[0]);  v0[3]=(short)f2bn(sY[0]);  v0[4]=(short)f2bn(sZ[0]);
    v0[5]=(short)f2bn(sX[1]);  v0[6]=(short)f2bn(sY[1]);  v0[7]=(short)f2bn(sZ[1]);
    v1[0]=(short)f2bn(sX[2]);  v1[1]=(short)f2bn(sY[2]);  v1[2]=(short)f2bn(sZ[2]);
    v1[3]=(short)f2bn(sX[3]);  v1[4]=(short)f2bn(sY[3]);  v1[5]=(short)f2bn(sZ[3]);
    v1[6]=(short)f2bn(sX[4]);  v1[7]=(short)f2bn(sY[4]);
    *(short8*)&arow[16] = v0; *(short8*)&arow[24] = v1;
    v0[0]=(short)f2bn(sZ[4]);  v0[1]=(short)f2bn(sX[5]);
    v0[2]=(short)f2bn(sY[5]);  v0[3]=(short)f2bn(sZ[5]);
    v0[4]=(short)f2bn(cX[0]);  v0[5]=(short)f2bn(cY[0]);  v0[6]=(short)f2bn(cZ[0]);
    v0[7]=(short)f2bn(cX[1]);
    v1[0]=(short)f2bn(cY[1]);  v1[1]=(short)f2bn(cZ[1]);
    v1[2]=(short)f2bn(cX[2]);  v1[3]=(short)f2bn(cY[2]);  v1[4]=(short)f2bn(cZ[2]);
    v1[5]=(short)f2bn(cX[3]);  v1[6]=(short)f2bn(cY[3]);  v1[7]=(short)f2bn(cZ[3]);
    *(short8*)&arow[32] = v0; *(short8*)&arow[40] = v1;
    v0[0]=(short)f2bn(cX[4]);  v0[1]=(short)f2bn(cY[4]);  v0[2]=(short)f2bn(cZ[4]);
    v0[3]=(short)f2bn(cX[5]);  v0[4]=(short)f2bn(cY[5]);  v0[5]=(short)f2bn(cZ[5]);
    v0[6]=0; v0[7]=0;
#pragma unroll
    for (int j = 0; j < 8; j++) v1[j] = 0;
    *(short8*)&arow[48] = v0; *(short8*)&arow[56] = v1;
  } else {
    short8 z;
#pragma unroll
    for (int j = 0; j < 8; j++) z[j] = 0;
#pragma unroll
    for (int c = 0; c < 8; c++) *(short8*)&arow[c*8] = z;
  }

  // ---- transmittance: wave shfl scan + cross-wave prefix ----
  float xv = fmaxf(1.0f - alpha, 1e-10f);
  float incl = xv;
#pragma unroll
  for (int off = 1; off < 64; off <<= 1){
    float y = __shfl_up(incl, off, 64);
    if (lane >= off) incl *= y;
  }
  float excl = __shfl_up(incl, 1, 64);
  if (lane == 0) excl = 1.0f;
  if (lane == 63) sh_wt[wv] = incl;
  __syncthreads();   // B1

  float pre = 1.0f;
#pragma unroll
  for (int k = 0; k < 4; k++) if (k < wv) pre *= sh_wt[k];
  const float last = sh_wt[0]*sh_wt[1]*sh_wt[2]*sh_wt[3];
  const float av = pre * excl;
  const float w  = alpha * av;
  sh_w[i] = w;

  float* outw = out + 36864;            // weights      (4096*256)
  float* outa = out + 36864 + 1048576;  // alphainv_cum (4096*257)
  outw[ray*NSAMP + i] = w;
  outa[ray*(NSAMP+1) + i] = av;
  if (i == NSAMP-1) outa[ray*(NSAMP+1) + NSAMP] = last;

  {
    float vals[5] = { w*t, w, w*nx, w*ny, w*nz };
#pragma unroll
    for (int v = 0; v < 5; v++){
      float s = vals[v];
#pragma unroll
      for (int m = 32; m > 0; m >>= 1) s += __shfl_xor(s, m, 64);
      if (lane == 0) red[wv][v] = s;
    }
  }
  __syncthreads();   // B2
  if (i == 0){
    float s0 = red[0][0]+red[1][0]+red[2][0]+red[3][0];
    float s1 = red[0][1]+red[1][1]+red[2][1]+red[3][1];
    float s2 = red[0][2]+red[1][2]+red[2][2]+red[3][2];
    float s3 = red[0][3]+red[1][3]+red[2][3]+red[3][3];
    float s4 = red[0][4]+red[1][4]+red[2][4]+red[3][4];
    const float dm = s0 + last * 3.0f;
    float* o1 = out + 12288; o1[ray] = dm;
    float* o2 = out + 16384; o2[ray] = 1.0f / dm;
    float* o3 = out + 20480; o3[ray] = s1;
    float* o4 = out + 24576;
    o4[ray*3+0] = s2; o4[ray*3+1] = s3; o4[ray*3+2] = s4;
  }

  // ---- MLP via MFMA: wave handles rows [wbase, wbase+64) ----
  const short8* fr = (const short8*)((const char*)wb + FRAG_BYTE_OFF);

#pragma unroll
  for (int l = 0; l < 3; l++){
    const int fbase = l * 512;
    f32x4 acc[4][4];
#pragma unroll
    for (int mt = 0; mt < 4; mt++)
#pragma unroll
      for (int nt = 0; nt < 4; nt++) acc[mt][nt] = (f32x4){0.f,0.f,0.f,0.f};

#pragma unroll
    for (int ks = 0; ks < 2; ks++){
      short8 a[4], b[4];
#pragma unroll
      for (int mt = 0; mt < 4; mt++)
        a[mt] = *(const short8*)&act[(wbase + mt*16 + n15)*72 + ks*32 + quad*8];
#pragma unroll
      for (int nt = 0; nt < 4; nt++)
        b[nt] = fr[fbase + (nt*2+ks)*64 + lane];
#pragma unroll
      for (int mt = 0; mt < 4; mt++)
#pragma unroll
        for (int nt = 0; nt < 4; nt++)
          acc[mt][nt] = __builtin_amdgcn_mfma_f32_16x16x32_bf16(a[mt], b[nt], acc[mt][nt], 0, 0, 0);
    }
    __syncthreads();
#pragma unroll
    for (int nt = 0; nt < 4; nt++){
      const float bn = wb[OBIAS + l*64 + nt*16 + n15];
#pragma unroll
      for (int mt = 0; mt < 4; mt++){
#pragma unroll
        for (int r = 0; r < 4; r++){
          float vv = fmaxf(acc[mt][nt][r] + bn, 0.0f);
          act[(wbase + mt*16 + quad*4 + r)*72 + nt*16 + n15] = f2bn(vv);
        }
      }
    }
    __syncthreads();
  }

  // layer 3 + fused weighted rgb reduction
  {
    f32x4 acc3[4];
#pragma unroll
    for (int mt = 0; mt < 4; mt++) acc3[mt] = (f32x4){0.f,0.f,0.f,0.f};
#pragma unroll
    for (int ks = 0; ks < 2; ks++){
      short8 a[4];
#pragma unroll
      for (int mt = 0; mt < 4; mt++)
        a[mt] = *(const short8*)&act[(wbase + mt*16 + n15)*72 + ks*32 + quad*8];
      short8 b = fr[1536 + ks*64 + lane];
#pragma unroll
      for (int mt = 0; mt < 4; mt++)
        acc3[mt] = __builtin_amdgcn_mfma_f32_16x16x32_bf16(a[mt], b, acc3[mt], 0, 0, 0);
    }
    const float bn3 = wb[OBIAS + 208 + n15];
    float p = 0.0f;
#pragma unroll
    for (int mt = 0; mt < 4; mt++){
#pragma unroll
      for (int r = 0; r < 4; r++){
        const float wr = sh_w[wbase + mt*16 + quad*4 + r];
        const float logit = acc3[mt][r] + bn3;
        p += wr * (1.0f / (1.0f + __expf(-logit)));
      }
    }
    p += __shfl_xor(p, 16, 64);
    p += __shfl_xor(p, 32, 64);
    if (lane < 16) red_rgb[wv][lane] = p;
  }
  __syncthreads();   // B3
  if (i < 3){
    float s = red_rgb[0][i] + red_rgb[1][i] + red_rgb[2][i] + red_rgb[3][i];
    out[ray*3+i] = s + last;   // + BG*last, BG=1
  }
}

// ================= fallback path (ws too small) =================
template<typename GT>
__device__ __forceinline__ void render_body(const GT* __restrict__ latent,
                                            const GT* __restrict__ normals,
                                            const float* __restrict__ wb,
                                            float* __restrict__ out)
{
  const int ray  = blockIdx.x;
  const int i    = threadIdx.x;
  const int lane = i & 63;
  const int wv   = i >> 6;
  const int quad = lane >> 4;
  const int n15  = lane & 15;
  const int wbase = wv * 64;

  __shared__ unsigned short act[NSAMP*72];
  __shared__ float sh_w[NSAMP];
  __shared__ float sh_wt[4];
  __shared__ float red[4][8];
  __shared__ float red_rgb[4][16];

  const float ox = wb[ORO+ray*3+0], oy = wb[ORO+ray*3+1], oz = wb[ORO+ray*3+2];
  const float dx = wb[ORD+ray*3+0], dy = wb[ORD+ray*3+1], dz = wb[ORD+ray*3+2];
  const float vx = wb[OVD+ray*3+0], vy = wb[OVD+ray*3+1], vz = wb[OVD+ray*3+2];

  const float t  = 0.2f + (2.8f/255.0f) * (float)i;
  const float px = ox + dx*t, py = oy + dy*t, pz = oz + dz*t;
  const bool inb = (px >= -1.0f) & (px <= 1.0f) & (py >= -1.0f) & (py <= 1.0f)
                 & (pz >= -1.0f) & (pz <= 1.0f);

  float alpha = 0.0f, nx = 0.0f, ny = 0.0f, nz = 0.0f;
  float fv[64];
#pragma unroll
  for (int k = 0; k < 64; k++) fv[k] = 0.0f;

  if (inb) {
    float ux = fminf(fmaxf((px+1.0f)*0.5f, 0.0f), 1.0f) * 127.0f;
    float uy = fminf(fmaxf((py+1.0f)*0.5f, 0.0f), 1.0f) * 127.0f;
    float uz = fminf(fmaxf((pz+1.0f)*0.5f, 0.0f), 1.0f) * 127.0f;
    int x0 = (int)floorf(ux); x0 = x0 > 126 ? 126 : (x0 < 0 ? 0 : x0);
    int y0 = (int)floorf(uy); y0 = y0 > 126 ? 126 : (y0 < 0 ? 0 : y0);
    int z0 = (int)floorf(uz); z0 = z0 > 126 ? 126 : (z0 < 0 ? 0 : z0);
    float fx = ux - (float)x0, fy = uy - (float)y0, fz = uz - (float)z0;
    const int base = x0*RS2 + y0*RESG + z0;
    const float gx = 1.0f - fx, gy = 1.0f - fy, gz = 1.0f - fz;
    const float w000 = gx*gy*gz, w100 = fx*gy*gz, w010 = gx*fy*gz, w001 = gx*gy*fz;
    const float w110 = fx*fy*gz, w101 = fx*gy*fz, w011 = gx*fy*fz, w111 = fx*fy*fz;

    float ch[19];
#pragma unroll
    for (int c = 0; c < 19; c++){
      const GT* g = (c < 16 ? latent + c*RS3 : normals + (c-16)*RS3) + base;
      ch[c] = w000*ldT(g,0)        + w100*ldT(g,RS2)
            + w010*ldT(g,RESG)     + w001*ldT(g,1)
            + w110*ldT(g,RS2+RESG) + w101*ldT(g,RS2+1)
            + w011*ldT(g,RESG+1)   + w111*ldT(g,RS2+RESG+1);
    }

    float xs = ch[0] + ACT_SHIFT;
    float sp = xs > 15.0f ? xs : log1pf(__expf(xs));
    alpha = 1.0f - __expf(-sp * 0.5f);

    float nn  = sqrtf(ch[16]*ch[16] + ch[17]*ch[17] + ch[18]*ch[18]);
    float ninv = 1.0f / fmaxf(nn, 1e-12f);
    nx = ch[16]*ninv; ny = ch[17]*ninv; nz = ch[18]*ninv;

    float dt = -(vx*nx + vy*ny + vz*nz);
    float rx = 2.0f*dt*nx + vx, ry = 2.0f*dt*ny + vy, rz = 2.0f*dt*nz + vz;

#pragma unroll
    for (int k = 0; k < 15; k++) fv[k] = ch[k+1];
    fv[15] = rx; fv[16] = ry; fv[17] = rz;
#pragma unroll
    for (int f = 0; f < 6; f++){
      float s = (float)(1 << f);
      fv[18 + f*3 + 0] = __sinf(rx*s);
      fv[18 + f*3 + 1] = __sinf(ry*s);
      fv[18 + f*3 + 2] = __sinf(rz*s);
      fv[36 + f*3 + 0] = __cosf(rx*s);
      fv[36 + f*3 + 1] = __cosf(ry*s);
      fv[36 + f*3 + 2] = __cosf(rz*s);
    }
  }

#pragma unroll
  for (int c = 0; c < 8; c++){
    short8 v;
#pragma unroll
    for (int k = 0; k < 8; k++) v[k] = (short)f2bu(fv[c*8+k]);
    *(short8*)&act[i*72 + c*8] = v;
  }

  float xvv = fmaxf(1.0f - alpha, 1e-10f);
  float incl = xvv;
#pragma unroll
  for (int off = 1; off < 64; off <<= 1){
    float y = __shfl_up(incl, off, 64);
    if (lane >= off) incl *= y;
  }
  float excl = __shfl_up(incl, 1, 64);
  if (lane == 0) excl = 1.0f;
  if (lane == 63) sh_wt[wv] = incl;
  __syncthreads();

  float pre = 1.0f;
#pragma unroll
  for (int k = 0; k < 4; k++) if (k < wv) pre *= sh_wt[k];
  const float last = sh_wt[0]*sh_wt[1]*sh_wt[2]*sh_wt[3];
  const float av = pre * excl;
  const float w  = alpha * av;
  sh_w[i] = w;

  float* outw = out + 36864;
  float* outa = out + 36864 + 1048576;
  outw[ray*NSAMP + i] = w;
  outa[ray*(NSAMP+1) + i] = av;
  if (i == NSAMP-1) outa[ray*(NSAMP+1) + NSAMP] = last;

  {
    float vals[5] = { w*t, w, w*nx, w*ny, w*nz };
#pragma unroll
    for (int v = 0; v < 5; v++){
      float s = vals[v];
#pragma unroll
      for (int m = 32; m > 0; m >>= 1) s += __shfl_xor(s, m, 64);
      if (lane == 0) red[wv][v] = s;
    }
  }
  __syncthreads();
  if (i == 0){
    float s0 = red[0][0]+red[1][0]+red[2][0]+red[3][0];
    float s1 = red[0][1]+red[1][1]+red[2][1]+red[3][1];
    float s2 = red[0][2]+red[1][2]+red[2][2]+red[3][2];
    float s3 = red[0][3]+red[1][3]+red[2][3]+red[3][3];
    float s4 = red[0][4]+red[1][4]+red[2][4]+red[3][4];
    const float dm = s0 + last * 3.0f;
    float* o1 = out + 12288; o1[ray] = dm;
    float* o2 = out + 16384; o2[ray] = 1.0f / dm;
    float* o3 = out + 20480; o3[ray] = s1;
    float* o4 = out + 24576;
    o4[ray*3+0] = s2; o4[ray*3+1] = s3; o4[ray*3+2] = s4;
  }

  const short8* fr = (const short8*)((const char*)wb + FRAG_BYTE_OFF);

#pragma unroll
  for (int l = 0; l < 3; l++){
    const int fbase = l * 512;
    f32x4 acc[4][4];
#pragma unroll
    for (int mt = 0; mt < 4; mt++)
#pragma unroll
      for (int nt = 0; nt < 4; nt++) acc[mt][nt] = (f32x4){0.f,0.f,0.f,0.f};

#pragma unroll
    for (int ks = 0; ks < 2; ks++){
      short8 a[4], b[4];
#pragma unroll
      for (int mt = 0; mt < 4; mt++)
        a[mt] = *(const short8*)&act[(wbase + mt*16 + n15)*72 + ks*32 + quad*8];
#pragma unroll
      for (int nt = 0; nt < 4; nt++)
        b[nt] = fr[fbase + (nt*2+ks)*64 + lane];
#pragma unroll
      for (int mt = 0; mt < 4; mt++)
#pragma unroll
        for (int nt = 0; nt < 4; nt++)
          acc[mt][nt] = __builtin_amdgcn_mfma_f32_16x16x32_bf16(a[mt], b[nt], acc[mt][nt], 0, 0, 0);
    }
    __syncthreads();
#pragma unroll
    for (int nt = 0; nt < 4; nt++){
      const float bn = wb[OBIAS + l*64 + nt*16 + n15];
#pragma unroll
      for (int mt = 0; mt < 4; mt++){
#pragma unroll
        for (int r = 0; r < 4; r++){
          float vv = fmaxf(acc[mt][nt][r] + bn, 0.0f);
          act[(wbase + mt*16 + quad*4 + r)*72 + nt*16 + n15] = f2bu(vv);
        }
      }
    }
    __syncthreads();
  }

  {
    f32x4 acc3[4];
#pragma unroll
    for (int mt = 0; mt < 4; mt++) acc3[mt] = (f32x4){0.f,0.f,0.f,0.f};
#pragma unroll
    for (int ks = 0; ks < 2; ks++){
      short8 a[4];
#pragma unroll
      for (int mt = 0; mt < 4; mt++)
        a[mt] = *(const short8*)&act[(wbase + mt*16 + n15)*72 + ks*32 + quad*8];
      short8 b = fr[1536 + ks*64 + lane];
#pragma unroll
      for (int mt = 0; mt < 4; mt++)
        acc3[mt] = __builtin_amdgcn_mfma_f32_16x16x32_bf16(a[mt], b, acc3[mt], 0, 0, 0);
    }
    const float bn3 = wb[OBIAS + 208 + n15];
    float p = 0.0f;
#pragma unroll
    for (int mt = 0; mt < 4; mt++){
#pragma unroll
      for (int r = 0; r < 4; r++){
        const float wr = sh_w[wbase + mt*16 + quad*4 + r];
        const float logit = acc3[mt][r] + bn3;
        p += wr * (1.0f / (1.0f + __expf(-logit)));
      }
    }
    p += __shfl_xor(p, 16, 64);
    p += __shfl_xor(p, 32, 64);
    if (lane < 16) red_rgb[wv][lane] = p;
  }
  __syncthreads();
  if (i < 3){
    float s = red_rgb[0][i] + red_rgb[1][i] + red_rgb[2][i] + red_rgb[3][i];
    out[ray*3+i] = s + last;
  }
}

__global__ __launch_bounds__(256)
void render_fallback(const void* __restrict__ latent, const void* __restrict__ normals,
                     const float* __restrict__ wb, float* __restrict__ out)
{
  if (wb[OFLAG] > 0.5f)
    render_body<float>((const float*)latent, (const float*)normals, wb, out);
  else
    render_body<bf16 >((const bf16*)latent,  (const bf16*)normals,  wb, out);
}

extern "C" void kernel_launch(void* const* d_in, const int* in_sizes, int n_in,
                              void* d_out, int out_size, void* d_ws, size_t ws_size,
                              hipStream_t stream)
{
  float* wb = (float*)d_ws;
  if (ws_size >= WS_NEED){
    stage<<<STAGE_BLOCKS, 256, 0, stream>>>(d_in[5], d_in[6], d_in[7], d_in[8],
                                            d_in[9], d_in[10], d_in[11], d_in[12],
                                            d_in[0], d_in[1], d_in[2],
                                            d_in[3], d_in[4], wb);
    render_fast<<<NRAYS, 256, 0, stream>>>(wb, (float*)d_out);
  } else {
    prep<<<PREP_BLOCKS, 256, 0, stream>>>(d_in[5], d_in[6], d_in[7], d_in[8],
                                          d_in[9], d_in[10], d_in[11], d_in[12],
                                          d_in[0], d_in[1], d_in[2], wb);
    render_fallback<<<NRAYS, 256, 0, stream>>>(d_in[3], d_in[4], wb, (float*)d_out);
  }
}